// Round 1
// baseline (6285.961 us; speedup 1.0000x reference)
//
#include <hip/hip_runtime.h>
#include <math.h>

#define NN 50000
#define NE 400000

// ---------------- workspace layout (bytes) ----------------
#define O_FLAG 0ULL
#define O_SRC  256ULL
#define O_DST  (O_SRC + 1600000ULL)           // E*4
#define O_Q1   (O_DST + 1600000ULL)
#define SZ_NM  51200000ULL                     // N*256*4
#define O_K1   (O_Q1 + SZ_NM)
#define O_V1   (O_K1 + SZ_NM)
#define O_S1M  (O_V1 + SZ_NM)                  // skip1
#define O_NUM1 (O_S1M + SZ_NM)                 // zeroed region start
#define O_S1S  (O_NUM1 + SZ_NM)                // N*8*4
#define O_NUM2 (O_S1S + 1600000ULL)            // N*32*4
#define O_S2S  (O_NUM2 + 6400000ULL)           // N*4
#define WS_TOTAL (O_S2S + 200000ULL)
#define ZERO_BYTES (SZ_NM + 1600000ULL + 6400000ULL + 200000ULL)
// aliases
#define O_H   O_Q1
#define O_Q2  O_K1
#define O_K2  (O_Q2 + 6400000ULL)
#define O_V2  (O_K2 + 6400000ULL)
#define O_S2M (O_V2 + 6400000ULL)

#define RSQRT32 0.17677669529663687f

__device__ __forceinline__ void atomAddF(float* p, float v) {
    unsafeAtomicAdd(p, v);
}

// ---------------- index dtype detect + convert ----------------
__global__ void k_detect(const unsigned int* ei, int* flag) {
    if (threadIdx.x == 0) {
        int is64 = 1;
        for (int i = 0; i < 64; ++i)
            if (ei[2 * i + 1] != 0u) { is64 = 0; break; }
        *flag = is64;
    }
}

__global__ void k_convert(const void* ei, const int* flag, int* srcI, int* dstI) {
    int i = blockIdx.x * 256 + threadIdx.x;
    if (i >= NE) return;
    if (*flag) {
        const long long* p = (const long long*)ei;
        srcI[i] = (int)p[i];
        dstI[i] = (int)p[NE + i];
    } else {
        const int* p = (const int*)ei;
        srcI[i] = p[i];
        dstI[i] = p[NE + i];
    }
}

// ---------------- node GEMM layer 1: x(50000x128) @ 4x(128x256) ----------------
__global__ __launch_bounds__(256) void k_gemm1(
    const float* __restrict__ x,
    const float* __restrict__ B0, const float* __restrict__ B1,
    const float* __restrict__ B2, const float* __restrict__ B3,
    const float* __restrict__ c0, const float* __restrict__ c1,
    const float* __restrict__ c2, const float* __restrict__ c3,
    float* __restrict__ O0, float* __restrict__ O1,
    float* __restrict__ O2, float* __restrict__ O3)
{
    __shared__ float As[64 * 132];
    __shared__ float Bs[128 * 68];
    const int t = threadIdx.x;
    const int row0 = blockIdx.x * 64;
    const int by = blockIdx.y;
    const int part = by >> 2;
    const int pcol0 = (by & 3) * 64;
    const float* Bp = part == 0 ? B0 : part == 1 ? B1 : part == 2 ? B2 : B3;
    const float* bp = part == 0 ? c0 : part == 1 ? c1 : part == 2 ? c2 : c3;
    float* Op = part == 0 ? O0 : part == 1 ? O1 : part == 2 ? O2 : O3;

    { // load A 64x128
        const int r = t >> 5;
        const int c = (t & 31) * 4;
        #pragma unroll
        for (int i = 0; i < 8; ++i) {
            const int rr = r + i * 8;
            const int gr = row0 + rr;
            float4 v = make_float4(0.f, 0.f, 0.f, 0.f);
            if (gr < NN) v = *(const float4*)(x + (size_t)gr * 128 + c);
            *(float4*)(As + rr * 132 + c) = v;
        }
    }
    { // load B 128x64
        const int r = t >> 4;
        const int c = (t & 15) * 4;
        #pragma unroll
        for (int i = 0; i < 8; ++i) {
            const int rr = r + i * 16;
            float4 v = *(const float4*)(Bp + (size_t)rr * 256 + pcol0 + c);
            *(float4*)(Bs + rr * 68 + c) = v;
        }
    }
    __syncthreads();
    const int ty = t >> 4, tx = t & 15;
    float acc[4][4] = {};
    #pragma unroll 4
    for (int k = 0; k < 128; k += 4) {
        float4 a4[4], bv[4];
        #pragma unroll
        for (int i = 0; i < 4; ++i) a4[i] = *(const float4*)(As + (4 * ty + i) * 132 + k);
        #pragma unroll
        for (int kk = 0; kk < 4; ++kk) bv[kk] = *(const float4*)(Bs + (k + kk) * 68 + 4 * tx);
        #pragma unroll
        for (int i = 0; i < 4; ++i) {
            const float* ap = (const float*)&a4[i];
            #pragma unroll
            for (int kk = 0; kk < 4; ++kk) {
                const float av = ap[kk];
                acc[i][0] += av * bv[kk].x;
                acc[i][1] += av * bv[kk].y;
                acc[i][2] += av * bv[kk].z;
                acc[i][3] += av * bv[kk].w;
            }
        }
    }
    const int gc = pcol0 + tx * 4;
    const float4 bias = *(const float4*)(bp + gc);
    #pragma unroll
    for (int i = 0; i < 4; ++i) {
        const int gr = row0 + 4 * ty + i;
        if (gr < NN) {
            float4 o = make_float4(acc[i][0] + bias.x, acc[i][1] + bias.y,
                                   acc[i][2] + bias.z, acc[i][3] + bias.w);
            *(float4*)(Op + (size_t)gr * 256 + gc) = o;
        }
    }
}

// ---------------- fused edge kernel, layer 1 ----------------
// 32 edges/block. Phase1: edge_attr in LDS. Phase2: e = attr @ We1 (LDS-staged W).
// Phase3: logits, exp (no max pass needed: |logit|~O(8)), atomic scatter.
__global__ __launch_bounds__(256) void k_edge1(
    const int* __restrict__ srcI, const int* __restrict__ dstI,
    const float* __restrict__ lu, const float* __restrict__ tE,
    const float* __restrict__ msg, const float* __restrict__ tw,
    const float* __restrict__ tb, const float* __restrict__ We1,
    const float* __restrict__ Q1, const float* __restrict__ K1,
    const float* __restrict__ V1,
    float* __restrict__ num1, float* __restrict__ s1)
{
    __shared__ __align__(16) char smem[50176];
    float* attr = (float*)smem;             // [32][132]
    float* Wc   = (float*)(smem + 16896);   // [32][260]
    float* e_s  = (float*)smem;             // [32][264] (phase 3, overlaps)

    const int t = threadIdx.x;
    const int e0 = blockIdx.x * 32;

    { // phase 1: edge_attr = [cos(rel_t*tw+tb) | msg]
        const int j = t >> 3, seg = t & 7;
        const int eg = e0 + j;
        if (seg < 4) {
            const int sI = srcI[eg];
            const float rt = lu[sI] - tE[eg];
            const int k0 = seg * 16;
            #pragma unroll
            for (int i = 0; i < 16; ++i) {
                const int k = k0 + i;
                attr[j * 132 + k] = __cosf(rt * tw[k] + tb[k]);
            }
        } else {
            const int m0 = (seg - 4) * 16;
            #pragma unroll
            for (int i = 0; i < 16; i += 4) {
                const float4 v = *(const float4*)(msg + (size_t)eg * 64 + m0 + i);
                *(float4*)(attr + j * 132 + 64 + m0 + i) = v;
            }
        }
    }

    // phase 2: e(32x256) = attr(32x128) @ We1(128x256); micro-tile 4 edges x 8 cols
    const int tr = t >> 5;   // 0..7 -> edges 4*tr..
    const int tc = t & 31;   // cols 4*tc and 128+4*tc
    float acc[4][8] = {};
    for (int k0 = 0; k0 < 128; k0 += 32) {
        if (k0) __syncthreads();
        { // stage W chunk [32][256]
            const int kk = t >> 3;
            const int cc = (t & 7) * 32;
            const float* gw = We1 + (size_t)(k0 + kk) * 256 + cc;
            float* lw = Wc + kk * 260 + cc;
            #pragma unroll
            for (int i = 0; i < 32; i += 4)
                *(float4*)(lw + i) = *(const float4*)(gw + i);
        }
        __syncthreads();
        #pragma unroll 4
        for (int kk = 0; kk < 32; ++kk) {
            float av[4];
            #pragma unroll
            for (int i = 0; i < 4; ++i) av[i] = attr[(4 * tr + i) * 132 + k0 + kk];
            const float4 w0 = *(const float4*)(Wc + kk * 260 + 4 * tc);
            const float4 w1 = *(const float4*)(Wc + kk * 260 + 128 + 4 * tc);
            const float wv[8] = {w0.x, w0.y, w0.z, w0.w, w1.x, w1.y, w1.z, w1.w};
            #pragma unroll
            for (int i = 0; i < 4; ++i)
                #pragma unroll
                for (int q = 0; q < 8; ++q)
                    acc[i][q] += av[i] * wv[q];
        }
    }
    __syncthreads();
    #pragma unroll
    for (int i = 0; i < 4; ++i) {
        *(float4*)(e_s + (4 * tr + i) * 264 + 4 * tc) =
            make_float4(acc[i][0], acc[i][1], acc[i][2], acc[i][3]);
        *(float4*)(e_s + (4 * tr + i) * 264 + 128 + 4 * tc) =
            make_float4(acc[i][4], acc[i][5], acc[i][6], acc[i][7]);
    }
    __syncthreads();

    { // phase 3: attention + atomic scatter. thread = (edge j, head hh)
        const int j = t >> 3, hh = t & 7;
        const int eg = e0 + j;
        const int sI = srcI[eg], dI = dstI[eg];
        const float* qrow = Q1 + (size_t)dI * 256 + hh * 32;
        const float* krow = K1 + (size_t)sI * 256 + hh * 32;
        const float* erow = e_s + j * 264 + hh * 32;
        float ebuf[32];
        float dotp = 0.f;
        #pragma unroll
        for (int c = 0; c < 32; c += 4) {
            const float4 e4 = *(const float4*)(erow + c);
            const float4 q4 = *(const float4*)(qrow + c);
            const float4 k4 = *(const float4*)(krow + c);
            ebuf[c + 0] = e4.x; ebuf[c + 1] = e4.y; ebuf[c + 2] = e4.z; ebuf[c + 3] = e4.w;
            dotp += q4.x * (k4.x + e4.x) + q4.y * (k4.y + e4.y) +
                    q4.z * (k4.z + e4.z) + q4.w * (k4.w + e4.w);
        }
        const float p = __expf(fminf(dotp * RSQRT32, 80.f));
        atomAddF(s1 + (size_t)dI * 8 + hh, p);
        const float* vrow = V1 + (size_t)sI * 256 + hh * 32;
        float* nrow = num1 + (size_t)dI * 256 + hh * 32;
        #pragma unroll
        for (int c = 0; c < 32; c += 4) {
            const float4 v4 = *(const float4*)(vrow + c);
            atomAddF(nrow + c + 0, p * (v4.x + ebuf[c + 0]));
            atomAddF(nrow + c + 1, p * (v4.y + ebuf[c + 1]));
            atomAddF(nrow + c + 2, p * (v4.z + ebuf[c + 2]));
            atomAddF(nrow + c + 3, p * (v4.w + ebuf[c + 3]));
        }
    }
}

// ---------------- finalize layer 1: h = relu(num/s + skip) ----------------
__global__ void k_fin1(const float* __restrict__ num1, const float* __restrict__ s1,
                       const float* __restrict__ S1m, float* __restrict__ h)
{
    const int i = blockIdx.x * 256 + threadIdx.x;   // over N*256
    const int n = i >> 8, c = i & 255;
    const float s = s1[n * 8 + (c >> 5)];
    const float v = num1[i] / (s + 1e-16f) + S1m[i];
    h[i] = v > 0.f ? v : 0.f;
}

// ---------------- node GEMM layer 2: h(50000x256) @ 4x(256x32) ----------------
__global__ __launch_bounds__(256) void k_gemm2(
    const float* __restrict__ hmat,
    const float* __restrict__ B0, const float* __restrict__ B1,
    const float* __restrict__ B2, const float* __restrict__ B3,
    const float* __restrict__ c0, const float* __restrict__ c1,
    const float* __restrict__ c2, const float* __restrict__ c3,
    float* __restrict__ O0, float* __restrict__ O1,
    float* __restrict__ O2, float* __restrict__ O3)
{
    __shared__ float As[32 * 68];
    __shared__ float Bs[64 * 132];
    const int t = threadIdx.x;
    const int row0 = blockIdx.x * 32;
    const int ty = t >> 5, tx = t & 31;
    float acc[4][4] = {};
    for (int k0 = 0; k0 < 256; k0 += 64) {
        { // load As 32x64
            const int r = t >> 4, c = (t & 15) * 4;
            #pragma unroll
            for (int i = 0; i < 2; ++i) {
                const int rr = r + i * 16;
                const int gr = row0 + rr;
                float4 v = make_float4(0.f, 0.f, 0.f, 0.f);
                if (gr < NN) v = *(const float4*)(hmat + (size_t)gr * 256 + k0 + c);
                *(float4*)(As + rr * 68 + c) = v;
            }
        }
        { // load Bs 64x128 (4 parts of 32 cols)
            const int r = t >> 5, c = (t & 31) * 4;
            const int part = c >> 5, pc = c & 31;
            const float* bsrc = part == 0 ? B0 : part == 1 ? B1 : part == 2 ? B2 : B3;
            #pragma unroll
            for (int i = 0; i < 8; ++i) {
                const int rr = r + i * 8;
                float4 v = *(const float4*)(bsrc + (size_t)(k0 + rr) * 32 + pc);
                *(float4*)(Bs + rr * 132 + c) = v;
            }
        }
        __syncthreads();
        #pragma unroll 4
        for (int k = 0; k < 64; k += 4) {
            float4 a4[4], bv[4];
            #pragma unroll
            for (int i = 0; i < 4; ++i) a4[i] = *(const float4*)(As + (4 * ty + i) * 68 + k);
            #pragma unroll
            for (int kk = 0; kk < 4; ++kk) bv[kk] = *(const float4*)(Bs + (k + kk) * 132 + 4 * tx);
            #pragma unroll
            for (int i = 0; i < 4; ++i) {
                const float* ap = (const float*)&a4[i];
                #pragma unroll
                for (int kk = 0; kk < 4; ++kk) {
                    const float av = ap[kk];
                    acc[i][0] += av * bv[kk].x;
                    acc[i][1] += av * bv[kk].y;
                    acc[i][2] += av * bv[kk].z;
                    acc[i][3] += av * bv[kk].w;
                }
            }
        }
        __syncthreads();
    }
    const int part = tx >> 3, pc = (tx & 7) * 4;
    const float* bb = part == 0 ? c0 : part == 1 ? c1 : part == 2 ? c2 : c3;
    float* Op = part == 0 ? O0 : part == 1 ? O1 : part == 2 ? O2 : O3;
    const float4 bias = *(const float4*)(bb + pc);
    #pragma unroll
    for (int i = 0; i < 4; ++i) {
        const int gr = row0 + 4 * ty + i;
        if (gr < NN) {
            float4 o = make_float4(acc[i][0] + bias.x, acc[i][1] + bias.y,
                                   acc[i][2] + bias.z, acc[i][3] + bias.w);
            *(float4*)(Op + (size_t)gr * 32 + pc) = o;
        }
    }
}

// ---------------- fused edge kernel, layer 2 (1 head, 32 ch) ----------------
__global__ __launch_bounds__(256) void k_edge2(
    const int* __restrict__ srcI, const int* __restrict__ dstI,
    const float* __restrict__ lu, const float* __restrict__ tE,
    const float* __restrict__ msg, const float* __restrict__ tw,
    const float* __restrict__ tb, const float* __restrict__ We2,
    const float* __restrict__ Q2, const float* __restrict__ K2,
    const float* __restrict__ V2,
    float* __restrict__ num2, float* __restrict__ s2)
{
    __shared__ __align__(16) float attr[32 * 132];
    __shared__ __align__(16) float W2s[128 * 36];
    const int t = threadIdx.x;
    const int e0 = blockIdx.x * 32;

    { // stage full We2 (128x32)
        const int k = t >> 1, half = t & 1;
        #pragma unroll
        for (int i = 0; i < 4; ++i) {
            const int c = half * 16 + i * 4;
            *(float4*)(W2s + k * 36 + c) = *(const float4*)(We2 + (size_t)k * 32 + c);
        }
    }
    { // edge_attr
        const int j = t >> 3, seg = t & 7;
        const int eg = e0 + j;
        if (seg < 4) {
            const int sI = srcI[eg];
            const float rt = lu[sI] - tE[eg];
            const int k0 = seg * 16;
            #pragma unroll
            for (int i = 0; i < 16; ++i) {
                const int k = k0 + i;
                attr[j * 132 + k] = __cosf(rt * tw[k] + tb[k]);
            }
        } else {
            const int m0 = (seg - 4) * 16;
            #pragma unroll
            for (int i = 0; i < 16; i += 4) {
                const float4 v = *(const float4*)(msg + (size_t)eg * 64 + m0 + i);
                *(float4*)(attr + j * 132 + 64 + m0 + i) = v;
            }
        }
    }
    __syncthreads();

    const int j = t >> 3, qq = t & 7;   // edge j, 4-col group qq
    const int eg = e0 + j;
    float acc[4] = {0.f, 0.f, 0.f, 0.f};
    #pragma unroll 4
    for (int k = 0; k < 128; ++k) {
        const float a = attr[j * 132 + k];
        const float4 w = *(const float4*)(W2s + k * 36 + 4 * qq);
        acc[0] += a * w.x; acc[1] += a * w.y; acc[2] += a * w.z; acc[3] += a * w.w;
    }
    const int sI = srcI[eg], dI = dstI[eg];
    const float4 q4 = *(const float4*)(Q2 + (size_t)dI * 32 + 4 * qq);
    const float4 k4 = *(const float4*)(K2 + (size_t)sI * 32 + 4 * qq);
    float dotp = q4.x * (k4.x + acc[0]) + q4.y * (k4.y + acc[1]) +
                 q4.z * (k4.z + acc[2]) + q4.w * (k4.w + acc[3]);
    dotp += __shfl_xor(dotp, 1);
    dotp += __shfl_xor(dotp, 2);
    dotp += __shfl_xor(dotp, 4);
    const float p = __expf(fminf(dotp * RSQRT32, 80.f));
    if (qq == 0) atomAddF(s2 + dI, p);
    const float4 v4 = *(const float4*)(V2 + (size_t)sI * 32 + 4 * qq);
    float* nr = num2 + (size_t)dI * 32 + 4 * qq;
    atomAddF(nr + 0, p * (v4.x + acc[0]));
    atomAddF(nr + 1, p * (v4.y + acc[1]));
    atomAddF(nr + 2, p * (v4.z + acc[2]));
    atomAddF(nr + 3, p * (v4.w + acc[3]));
}

// ---------------- finalize layer 2 ----------------
__global__ void k_fin2(const float* __restrict__ num2, const float* __restrict__ s2,
                       const float* __restrict__ S2m, float* __restrict__ out)
{
    const int i = blockIdx.x * 256 + threadIdx.x;   // over N*32
    const int n = i >> 5;
    const float s = s2[n];
    const float v = num2[i] / (s + 1e-16f) + S2m[i];
    out[i] = v > 0.f ? v : 0.f;
}

extern "C" void kernel_launch(void* const* d_in, const int* in_sizes, int n_in,
                              void* d_out, int out_size, void* d_ws, size_t ws_size,
                              hipStream_t stream) {
    const float* x   = (const float*)d_in[0];
    const float* lu  = (const float*)d_in[1];
    const void*  ei  = d_in[2];
    const float* tE  = (const float*)d_in[3];
    const float* msg = (const float*)d_in[4];
    const float* tw  = (const float*)d_in[5];
    const float* tb  = (const float*)d_in[6];
    const float* Wq1 = (const float*)d_in[7];  const float* bq1 = (const float*)d_in[8];
    const float* Wk1 = (const float*)d_in[9];  const float* bk1 = (const float*)d_in[10];
    const float* Wv1 = (const float*)d_in[11]; const float* bv1 = (const float*)d_in[12];
    const float* We1 = (const float*)d_in[13];
    const float* Ws1 = (const float*)d_in[14]; const float* bs1 = (const float*)d_in[15];
    const float* Wq2 = (const float*)d_in[16]; const float* bq2 = (const float*)d_in[17];
    const float* Wk2 = (const float*)d_in[18]; const float* bk2 = (const float*)d_in[19];
    const float* Wv2 = (const float*)d_in[20]; const float* bv2 = (const float*)d_in[21];
    const float* We2 = (const float*)d_in[22];
    const float* Ws2 = (const float*)d_in[23]; const float* bs2 = (const float*)d_in[24];
    float* out = (float*)d_out;
    char* ws = (char*)d_ws;

    if (ws_size < WS_TOTAL) return;  // workspace too small; bench will show wrong-answer

    int* flag = (int*)(ws + O_FLAG);
    int* srcI = (int*)(ws + O_SRC);
    int* dstI = (int*)(ws + O_DST);
    float* Q1   = (float*)(ws + O_Q1);
    float* K1m  = (float*)(ws + O_K1);
    float* V1   = (float*)(ws + O_V1);
    float* S1m  = (float*)(ws + O_S1M);
    float* num1 = (float*)(ws + O_NUM1);
    float* s1   = (float*)(ws + O_S1S);
    float* num2 = (float*)(ws + O_NUM2);
    float* s2   = (float*)(ws + O_S2S);
    float* hbuf = (float*)(ws + O_H);
    float* Q2   = (float*)(ws + O_Q2);
    float* K2m  = (float*)(ws + O_K2);
    float* V2   = (float*)(ws + O_V2);
    float* S2m  = (float*)(ws + O_S2M);

    hipMemsetAsync(ws + O_NUM1, 0, ZERO_BYTES, stream);
    k_detect<<<1, 64, 0, stream>>>((const unsigned int*)ei, flag);
    k_convert<<<(NE + 255) / 256, 256, 0, stream>>>(ei, flag, srcI, dstI);
    k_gemm1<<<dim3((NN + 63) / 64, 16), 256, 0, stream>>>(
        x, Wq1, Wk1, Wv1, Ws1, bq1, bk1, bv1, bs1, Q1, K1m, V1, S1m);
    k_edge1<<<NE / 32, 256, 0, stream>>>(
        srcI, dstI, lu, tE, msg, tw, tb, We1, Q1, K1m, V1, num1, s1);
    k_fin1<<<(NN * 256) / 256, 256, 0, stream>>>(num1, s1, S1m, hbuf);
    k_gemm2<<<(NN + 31) / 32, 256, 0, stream>>>(
        hbuf, Wq2, Wk2, Wv2, Ws2, bq2, bk2, bv2, bs2, Q2, K2m, V2, S2m);
    k_edge2<<<NE / 32, 256, 0, stream>>>(
        srcI, dstI, lu, tE, msg, tw, tb, We2, Q2, K2m, V2, num2, s2);
    k_fin2<<<(NN * 32) / 256, 256, 0, stream>>>(num2, s2, S2m, out);
}

// Round 2
// 1378.437 us; speedup vs baseline: 4.5602x; 4.5602x over previous
//
#include <hip/hip_runtime.h>
#include <math.h>

#define NN 50000
#define NE 400000
#define RSQRT32 0.17677669529663687f

// ---------------- workspace layout (bytes) ----------------
#define O_FLAG  0ULL
#define O_SRC   256ULL                          // E*4
#define O_DST   (O_SRC  + 1600000ULL)           // E*4
#define O_DEG   (O_DST  + 1600000ULL)           // N*4
#define O_CUR   (O_DEG  + 200000ULL)            // N*4
#define O_START (O_CUR  + 200000ULL)            // (N+1)*4 padded
#define O_SRCS  (O_START + 200192ULL)           // E*4
#define O_DSTS  (O_SRCS + 1600000ULL)           // E*4
#define O_ORIG  (O_DSTS + 1600000ULL)           // E*4
#define O_RELT  (O_ORIG + 1600000ULL)           // E*4
#define O_Q1    (O_RELT + 1600000ULL)           // N*256*4 fp32 (later: Q2/K2/V2/S2m)
#define O_K1    (O_Q1  + 51200000ULL)           // N*256*2 bf16
#define O_V1    (O_K1  + 25600000ULL)           // bf16
#define O_S1M   (O_V1  + 25600000ULL)           // bf16
#define O_E2P   (O_S1M + 25600000ULL)           // E*32*2 bf16
#define O_NUM1  (O_E2P + 25600000ULL)           // N*256*4 fp32 (becomes h in-place)
#define O_S1S   (O_NUM1 + 51200000ULL)          // N*8*4
#define O_NUM2  (O_S1S + 1600000ULL)            // N*32*4
#define O_S2S   (O_NUM2 + 6400000ULL)           // N*4
#define WS_TOTAL (O_S2S + 200000ULL)
#define ZERO_BYTES (51200000ULL + 1600000ULL + 6400000ULL + 200000ULL)  // num1..s2 contiguous
// layer-2 node-GEMM outputs alias the dead Q1 region
#define O_Q2   O_Q1
#define O_K2   (O_Q2 + 6400000ULL)
#define O_V2   (O_K2 + 6400000ULL)
#define O_S2M  (O_V2 + 6400000ULL)

__device__ __forceinline__ void atomAddF(float* p, float v) { unsafeAtomicAdd(p, v); }

__device__ __forceinline__ unsigned short f2bf(float f) {
    unsigned int u = __float_as_uint(f);
    unsigned int r = (u + 0x7fffu + ((u >> 16) & 1u)) >> 16;
    return (unsigned short)r;
}
__device__ __forceinline__ float bf2f(unsigned short u) {
    return __uint_as_float(((unsigned int)u) << 16);
}
__device__ __forceinline__ float4 ld_bf16x4(const unsigned short* p) {
    const ushort4 u = *(const ushort4*)p;
    float4 r;
    r.x = bf2f(u.x); r.y = bf2f(u.y); r.z = bf2f(u.z); r.w = bf2f(u.w);
    return r;
}

// ---------------- index dtype detect + convert ----------------
__global__ void k_detect(const unsigned int* ei, int* flag) {
    if (threadIdx.x == 0) {
        int is64 = 1;
        for (int i = 0; i < 64; ++i)
            if (ei[2 * i + 1] != 0u) { is64 = 0; break; }
        *flag = is64;
    }
}

__global__ void k_convert(const void* ei, const int* flag, int* srcI, int* dstI) {
    int i = blockIdx.x * 256 + threadIdx.x;
    if (i >= NE) return;
    if (*flag) {
        const long long* p = (const long long*)ei;
        srcI[i] = (int)p[i];
        dstI[i] = (int)p[NE + i];
    } else {
        const int* p = (const int*)ei;
        srcI[i] = p[i];
        dstI[i] = p[NE + i];
    }
}

// ---------------- counting sort by dst ----------------
__global__ void k_hist(const int* __restrict__ dstI, int* __restrict__ deg) {
    int i = blockIdx.x * 256 + threadIdx.x;
    if (i < NE) atomicAdd(&deg[dstI[i]], 1);
}

#define NCHUNK 196  // ceil(50000/256)
__global__ void k_scan(const int* __restrict__ deg, int* __restrict__ start,
                       int* __restrict__ cursor) {
    __shared__ int sums[256];
    const int t = threadIdx.x;
    const int c0 = t * NCHUNK;
    int s = 0;
    for (int i = 0; i < NCHUNK; ++i) { int g = c0 + i; if (g < NN) s += deg[g]; }
    sums[t] = s;
    __syncthreads();
    for (int off = 1; off < 256; off <<= 1) {
        int v = (t >= off) ? sums[t - off] : 0;
        __syncthreads();
        sums[t] += v;
        __syncthreads();
    }
    int run = sums[t] - s;   // exclusive prefix for this chunk
    for (int i = 0; i < NCHUNK; ++i) {
        int g = c0 + i;
        if (g < NN) { start[g] = run; cursor[g] = run; run += deg[g]; }
        else if (g == NN) start[NN] = run;
    }
}

__global__ void k_scatter(const int* __restrict__ srcI, const int* __restrict__ dstI,
                          const float* __restrict__ lu, const float* __restrict__ tE,
                          int* __restrict__ cursor,
                          int* __restrict__ srcS, int* __restrict__ dstS,
                          int* __restrict__ orig, float* __restrict__ relT) {
    int i = blockIdx.x * 256 + threadIdx.x;
    if (i >= NE) return;
    const int d = dstI[i];
    const int s = srcI[i];
    const int pos = atomicAdd(&cursor[d], 1);
    srcS[pos] = s;
    dstS[pos] = d;
    orig[pos] = i;
    relT[pos] = lu[s] - tE[i];
}

// ---------------- node GEMM layer 1: x(50000x128) @ 4x(128x256) ----------------
// parts: 0=Q1(fp32) 1=K1(bf16) 2=V1(bf16) 3=S1m(bf16)
__global__ __launch_bounds__(256) void k_gemm1(
    const float* __restrict__ x,
    const float* __restrict__ B0, const float* __restrict__ B1,
    const float* __restrict__ B2, const float* __restrict__ B3,
    const float* __restrict__ c0, const float* __restrict__ c1,
    const float* __restrict__ c2, const float* __restrict__ c3,
    float* __restrict__ Q1, unsigned short* __restrict__ K1b,
    unsigned short* __restrict__ V1b, unsigned short* __restrict__ S1mb)
{
    __shared__ float As[64 * 132];
    __shared__ float Bs[128 * 68];
    const int t = threadIdx.x;
    const int row0 = blockIdx.x * 64;
    const int by = blockIdx.y;
    const int part = by >> 2;
    const int pcol0 = (by & 3) * 64;
    const float* Bp = part == 0 ? B0 : part == 1 ? B1 : part == 2 ? B2 : B3;
    const float* bp = part == 0 ? c0 : part == 1 ? c1 : part == 2 ? c2 : c3;

    { // load A 64x128
        const int r = t >> 5;
        const int c = (t & 31) * 4;
        #pragma unroll
        for (int i = 0; i < 8; ++i) {
            const int rr = r + i * 8;
            const int gr = row0 + rr;
            float4 v = make_float4(0.f, 0.f, 0.f, 0.f);
            if (gr < NN) v = *(const float4*)(x + (size_t)gr * 128 + c);
            *(float4*)(As + rr * 132 + c) = v;
        }
    }
    { // load B 128x64
        const int r = t >> 4;
        const int c = (t & 15) * 4;
        #pragma unroll
        for (int i = 0; i < 8; ++i) {
            const int rr = r + i * 16;
            float4 v = *(const float4*)(Bp + (size_t)rr * 256 + pcol0 + c);
            *(float4*)(Bs + rr * 68 + c) = v;
        }
    }
    __syncthreads();
    const int ty = t >> 4, tx = t & 15;
    float acc[4][4] = {};
    #pragma unroll 4
    for (int k = 0; k < 128; k += 4) {
        float4 a4[4], bv[4];
        #pragma unroll
        for (int i = 0; i < 4; ++i) a4[i] = *(const float4*)(As + (4 * ty + i) * 132 + k);
        #pragma unroll
        for (int kk = 0; kk < 4; ++kk) bv[kk] = *(const float4*)(Bs + (k + kk) * 68 + 4 * tx);
        #pragma unroll
        for (int i = 0; i < 4; ++i) {
            const float* ap = (const float*)&a4[i];
            #pragma unroll
            for (int kk = 0; kk < 4; ++kk) {
                const float av = ap[kk];
                acc[i][0] += av * bv[kk].x;
                acc[i][1] += av * bv[kk].y;
                acc[i][2] += av * bv[kk].z;
                acc[i][3] += av * bv[kk].w;
            }
        }
    }
    const int gc = pcol0 + tx * 4;
    const float4 bias = *(const float4*)(bp + gc);
    unsigned short* Ob = part == 1 ? K1b : part == 2 ? V1b : S1mb;
    #pragma unroll
    for (int i = 0; i < 4; ++i) {
        const int gr = row0 + 4 * ty + i;
        if (gr < NN) {
            float4 o = make_float4(acc[i][0] + bias.x, acc[i][1] + bias.y,
                                   acc[i][2] + bias.z, acc[i][3] + bias.w);
            if (part == 0) {
                *(float4*)(Q1 + (size_t)gr * 256 + gc) = o;
            } else {
                ushort4 u;
                u.x = f2bf(o.x); u.y = f2bf(o.y); u.z = f2bf(o.z); u.w = f2bf(o.w);
                *(ushort4*)(Ob + (size_t)gr * 256 + gc) = u;
            }
        }
    }
}

// ---------------- fused edge kernel layer 1 (sorted edges, segmented reduce) ----
// 32 edges/block, 256 threads.
// smem layout: [0:50304] attr(32x132f)+Wc(32x260f), overlapped by e_s(32x264f)
//              [50304] Wc2(32x33f) [54528] p_s(32x8f) [55552] d_s(32i)
__global__ __launch_bounds__(256) void k_edge1s(
    const int* __restrict__ srcS, const int* __restrict__ dstS,
    const int* __restrict__ orig, const float* __restrict__ relT,
    const float* __restrict__ msg, const float* __restrict__ tw,
    const float* __restrict__ tb, const float* __restrict__ We1,
    const float* __restrict__ We2,
    const float* __restrict__ Q1, const unsigned short* __restrict__ K1b,
    const unsigned short* __restrict__ V1b,
    float* __restrict__ num1, float* __restrict__ s1,
    unsigned short* __restrict__ e2p)
{
    __shared__ __align__(16) char smem[55680];
    float* attr = (float*)smem;               // [32][132]
    float* Wc   = (float*)(smem + 16896);     // [32][260]
    float* e_s  = (float*)smem;               // [32][264] (after phase 2)
    float* Wc2  = (float*)(smem + 50304);     // [32][33]
    float* p_s  = (float*)(smem + 54528);     // [32][8]
    int*   d_s  = (int*)(smem + 55552);       // [32]

    const int t = threadIdx.x;
    const int e0 = blockIdx.x * 32;

    if (t < 32) d_s[t] = dstS[e0 + t];

    { // phase 1: edge_attr = [cos(relT*tw+tb) | msg[orig]]
        const int j = t >> 3, seg = t & 7;
        const int eg = e0 + j;
        if (seg < 4) {
            const float rt = relT[eg];
            const int k0 = seg * 16;
            #pragma unroll
            for (int i = 0; i < 16; ++i) {
                const int k = k0 + i;
                attr[j * 132 + k] = __cosf(rt * tw[k] + tb[k]);
            }
        } else {
            const int oe = orig[eg];
            const int m0 = (seg - 4) * 16;
            #pragma unroll
            for (int i = 0; i < 16; i += 4) {
                const float4 v = *(const float4*)(msg + (size_t)oe * 64 + m0 + i);
                *(float4*)(attr + j * 132 + 64 + m0 + i) = v;
            }
        }
    }

    // phase 2: e(32x256) = attr @ We1; e2(32x32) = attr @ We2
    const int tr = t >> 5;   // edge group: rows 4*tr..4*tr+3
    const int tc = t & 31;   // cols 4*tc / 128+4*tc of We1; col tc of We2
    float acc[4][8] = {};
    float acc2[4] = {};
    for (int k0 = 0; k0 < 128; k0 += 32) {
        if (k0) __syncthreads();
        { // stage We1 chunk [32][256]
            const int kk = t >> 3;
            const int cc = (t & 7) * 32;
            const float* gw = We1 + (size_t)(k0 + kk) * 256 + cc;
            float* lw = Wc + kk * 260 + cc;
            #pragma unroll
            for (int i = 0; i < 32; i += 4)
                *(float4*)(lw + i) = *(const float4*)(gw + i);
        }
        { // stage We2 chunk [32][32]
            const int kk = t >> 3;
            const int cc = (t & 7) * 4;
            *(float4*)(Wc2 + kk * 33 + cc) = *(const float4*)(We2 + (size_t)(k0 + kk) * 32 + cc);
        }
        __syncthreads();
        #pragma unroll 4
        for (int kk = 0; kk < 32; ++kk) {
            float av[4];
            #pragma unroll
            for (int i = 0; i < 4; ++i) av[i] = attr[(4 * tr + i) * 132 + k0 + kk];
            const float4 w0 = *(const float4*)(Wc + kk * 260 + 4 * tc);
            const float4 w1 = *(const float4*)(Wc + kk * 260 + 128 + 4 * tc);
            const float w2 = Wc2[kk * 33 + tc];
            const float wv[8] = {w0.x, w0.y, w0.z, w0.w, w1.x, w1.y, w1.z, w1.w};
            #pragma unroll
            for (int i = 0; i < 4; ++i) {
                #pragma unroll
                for (int q = 0; q < 8; ++q)
                    acc[i][q] += av[i] * wv[q];
                acc2[i] += av[i] * w2;
            }
        }
    }
    __syncthreads();
    // store e2p (bf16, E x 32)
    #pragma unroll
    for (int i = 0; i < 4; ++i)
        e2p[(size_t)(e0 + 4 * tr + i) * 32 + tc] = f2bf(acc2[i]);
    // spill e to LDS (overwrites attr/Wc)
    #pragma unroll
    for (int i = 0; i < 4; ++i) {
        *(float4*)(e_s + (4 * tr + i) * 264 + 4 * tc) =
            make_float4(acc[i][0], acc[i][1], acc[i][2], acc[i][3]);
        *(float4*)(e_s + (4 * tr + i) * 264 + 128 + 4 * tc) =
            make_float4(acc[i][4], acc[i][5], acc[i][6], acc[i][7]);
    }
    __syncthreads();

    { // phase 3: attention weights; e_s <- p*(v+e). thread = (edge j, head hh)
        const int j = t >> 3, hh = t & 7;
        const int eg = e0 + j;
        const int sI = srcS[eg];
        const int dI = d_s[j];
        const float* qrow = Q1 + (size_t)dI * 256 + hh * 32;
        const unsigned short* krow = K1b + (size_t)sI * 256 + hh * 32;
        float4 ebuf[8];
        float dotp = 0.f;
        #pragma unroll
        for (int i = 0; i < 8; ++i) {
            const int c = (4 * i + 4 * hh) & 31;   // hh-rotated: breaks LDS bank aliasing
            const float4 e4 = *(const float4*)(e_s + j * 264 + hh * 32 + c);
            const float4 q4 = *(const float4*)(qrow + c);
            const float4 k4 = ld_bf16x4(krow + c);
            ebuf[i] = e4;
            dotp += q4.x * (k4.x + e4.x) + q4.y * (k4.y + e4.y) +
                    q4.z * (k4.z + e4.z) + q4.w * (k4.w + e4.w);
        }
        const float p = __expf(fminf(dotp * RSQRT32, 80.f));
        p_s[j * 8 + hh] = p;
        const unsigned short* vrow = V1b + (size_t)sI * 256 + hh * 32;
        #pragma unroll
        for (int i = 0; i < 8; ++i) {
            const int c = (4 * i + 4 * hh) & 31;
            const float4 v4 = ld_bf16x4(vrow + c);
            *(float4*)(e_s + j * 264 + hh * 32 + c) =
                make_float4(p * (v4.x + ebuf[i].x), p * (v4.y + ebuf[i].y),
                            p * (v4.z + ebuf[i].z), p * (v4.w + ebuf[i].w));
        }
    }
    __syncthreads();

    { // phase 4: segmented reduction over dst runs, one atomic per (run, channel)
        int r0 = 0;
        while (r0 < 32) {
            const int d = d_s[r0];
            int r1 = r0 + 1;
            while (r1 < 32 && d_s[r1] == d) ++r1;
            float a = 0.f;
            for (int j = r0; j < r1; ++j) a += e_s[j * 264 + t];
            atomAddF(num1 + (size_t)d * 256 + t, a);
            if (t < 8) {
                float sp = 0.f;
                for (int j = r0; j < r1; ++j) sp += p_s[j * 8 + t];
                atomAddF(s1 + (size_t)d * 8 + t, sp);
            }
            r0 = r1;
        }
    }
}

// ---------------- finalize layer 1 (in-place num1 -> h) ----------------
__global__ void k_fin1(float* __restrict__ num1, const float* __restrict__ s1,
                       const unsigned short* __restrict__ S1mb)
{
    const int i = blockIdx.x * 256 + threadIdx.x;   // N*256
    const int n = i >> 8, c = i & 255;
    const float s = s1[(n << 3) + (c >> 5)];
    const float v = num1[i] / (s + 1e-16f) + bf2f(S1mb[i]);
    num1[i] = v > 0.f ? v : 0.f;
}

// ---------------- node GEMM layer 2: h(50000x256) @ 4x(256x32) ----------------
__global__ __launch_bounds__(256) void k_gemm2(
    const float* __restrict__ hmat,
    const float* __restrict__ B0, const float* __restrict__ B1,
    const float* __restrict__ B2, const float* __restrict__ B3,
    const float* __restrict__ c0, const float* __restrict__ c1,
    const float* __restrict__ c2, const float* __restrict__ c3,
    float* __restrict__ O0, float* __restrict__ O1,
    float* __restrict__ O2, float* __restrict__ O3)
{
    __shared__ float As[32 * 68];
    __shared__ float Bs[64 * 132];
    const int t = threadIdx.x;
    const int row0 = blockIdx.x * 32;
    const int ty = t >> 5, tx = t & 31;
    float acc[4][4] = {};
    for (int k0 = 0; k0 < 256; k0 += 64) {
        if (k0) __syncthreads();
        { // load As 32x64
            const int r = t >> 4, c = (t & 15) * 4;
            #pragma unroll
            for (int i = 0; i < 2; ++i) {
                const int rr = r + i * 16;
                const int gr = row0 + rr;
                float4 v = make_float4(0.f, 0.f, 0.f, 0.f);
                if (gr < NN) v = *(const float4*)(hmat + (size_t)gr * 256 + k0 + c);
                *(float4*)(As + rr * 68 + c) = v;
            }
        }
        { // load Bs 64x128
            const int r = t >> 5, c = (t & 31) * 4;
            const int part = c >> 5, pc = c & 31;
            const float* bsrc = part == 0 ? B0 : part == 1 ? B1 : part == 2 ? B2 : B3;
            #pragma unroll
            for (int i = 0; i < 8; ++i) {
                const int rr = r + i * 8;
                float4 v = *(const float4*)(bsrc + (size_t)(k0 + rr) * 32 + pc);
                *(float4*)(Bs + rr * 132 + c) = v;
            }
        }
        __syncthreads();
        #pragma unroll 4
        for (int k = 0; k < 64; k += 4) {
            float4 a4[4], bv[4];
            #pragma unroll
            for (int i = 0; i < 4; ++i) a4[i] = *(const float4*)(As + (4 * ty + i) * 68 + k);
            #pragma unroll
            for (int kk = 0; kk < 4; ++kk) bv[kk] = *(const float4*)(Bs + (k + kk) * 132 + 4 * tx);
            #pragma unroll
            for (int i = 0; i < 4; ++i) {
                const float* ap = (const float*)&a4[i];
                #pragma unroll
                for (int kk = 0; kk < 4; ++kk) {
                    const float av = ap[kk];
                    acc[i][0] += av * bv[kk].x;
                    acc[i][1] += av * bv[kk].y;
                    acc[i][2] += av * bv[kk].z;
                    acc[i][3] += av * bv[kk].w;
                }
            }
        }
    }
    const int part = tx >> 3, pc = (tx & 7) * 4;
    const float* bb = part == 0 ? c0 : part == 1 ? c1 : part == 2 ? c2 : c3;
    float* Op = part == 0 ? O0 : part == 1 ? O1 : part == 2 ? O2 : O3;
    const float4 bias = *(const float4*)(bb + pc);
    #pragma unroll
    for (int i = 0; i < 4; ++i) {
        const int gr = row0 + 4 * ty + i;
        if (gr < NN) {
            float4 o = make_float4(acc[i][0] + bias.x, acc[i][1] + bias.y,
                                   acc[i][2] + bias.z, acc[i][3] + bias.w);
            *(float4*)(Op + (size_t)gr * 32 + pc) = o;
        }
    }
}

// ---------------- fused edge kernel layer 2 (sorted, segmented reduce) --------
__global__ __launch_bounds__(256) void k_edge2s(
    const int* __restrict__ srcS, const int* __restrict__ dstS,
    const unsigned short* __restrict__ e2p,
    const float* __restrict__ Q2, const float* __restrict__ K2,
    const float* __restrict__ V2,
    float* __restrict__ num2, float* __restrict__ s2)
{
    __shared__ float wt[32 * 36];
    __shared__ float ps[32];
    __shared__ int ds2[32];
    const int t = threadIdx.x;
    const int e0 = blockIdx.x * 32;
    if (t < 32) ds2[t] = dstS[e0 + t];

    const int j = t >> 3, qq = t & 7;
    const int eg = e0 + j;
    const int sI = srcS[eg];
    const int dI = dstS[eg];
    const float4 e4 = ld_bf16x4(e2p + (size_t)eg * 32 + 4 * qq);
    const float4 q4 = *(const float4*)(Q2 + (size_t)dI * 32 + 4 * qq);
    const float4 k4 = *(const float4*)(K2 + (size_t)sI * 32 + 4 * qq);
    float dotp = q4.x * (k4.x + e4.x) + q4.y * (k4.y + e4.y) +
                 q4.z * (k4.z + e4.z) + q4.w * (k4.w + e4.w);
    dotp += __shfl_xor(dotp, 1);
    dotp += __shfl_xor(dotp, 2);
    dotp += __shfl_xor(dotp, 4);
    const float p = __expf(fminf(dotp * RSQRT32, 80.f));
    if (qq == 0) ps[j] = p;
    const float4 v4 = *(const float4*)(V2 + (size_t)sI * 32 + 4 * qq);
    *(float4*)(wt + j * 36 + 4 * qq) =
        make_float4(p * (v4.x + e4.x), p * (v4.y + e4.y),
                    p * (v4.z + e4.z), p * (v4.w + e4.w));
    __syncthreads();

    int r0 = 0;
    while (r0 < 32) {
        const int d = ds2[r0];
        int r1 = r0 + 1;
        while (r1 < 32 && ds2[r1] == d) ++r1;
        if (t < 32) {
            float a = 0.f;
            for (int jj = r0; jj < r1; ++jj) a += wt[jj * 36 + t];
            atomAddF(num2 + (size_t)d * 32 + t, a);
        } else if (t == 32) {
            float sp = 0.f;
            for (int jj = r0; jj < r1; ++jj) sp += ps[jj];
            atomAddF(s2 + d, sp);
        }
        r0 = r1;
    }
}

// ---------------- finalize layer 2 ----------------
__global__ void k_fin2(const float* __restrict__ num2, const float* __restrict__ s2,
                       const float* __restrict__ S2m, float* __restrict__ out)
{
    const int i = blockIdx.x * 256 + threadIdx.x;   // N*32
    const int n = i >> 5;
    const float s = s2[n];
    const float v = num2[i] / (s + 1e-16f) + S2m[i];
    out[i] = v > 0.f ? v : 0.f;
}

extern "C" void kernel_launch(void* const* d_in, const int* in_sizes, int n_in,
                              void* d_out, int out_size, void* d_ws, size_t ws_size,
                              hipStream_t stream) {
    const float* x   = (const float*)d_in[0];
    const float* lu  = (const float*)d_in[1];
    const void*  ei  = d_in[2];
    const float* tE  = (const float*)d_in[3];
    const float* msg = (const float*)d_in[4];
    const float* tw  = (const float*)d_in[5];
    const float* tb  = (const float*)d_in[6];
    const float* Wq1 = (const float*)d_in[7];  const float* bq1 = (const float*)d_in[8];
    const float* Wk1 = (const float*)d_in[9];  const float* bk1 = (const float*)d_in[10];
    const float* Wv1 = (const float*)d_in[11]; const float* bv1 = (const float*)d_in[12];
    const float* We1 = (const float*)d_in[13];
    const float* Ws1 = (const float*)d_in[14]; const float* bs1 = (const float*)d_in[15];
    const float* Wq2 = (const float*)d_in[16]; const float* bq2 = (const float*)d_in[17];
    const float* Wk2 = (const float*)d_in[18]; const float* bk2 = (const float*)d_in[19];
    const float* Wv2 = (const float*)d_in[20]; const float* bv2 = (const float*)d_in[21];
    const float* We2 = (const float*)d_in[22];
    const float* Ws2 = (const float*)d_in[23]; const float* bs2 = (const float*)d_in[24];
    float* out = (float*)d_out;
    char* ws = (char*)d_ws;

    if (ws_size < WS_TOTAL) return;

    int* flag   = (int*)(ws + O_FLAG);
    int* srcI   = (int*)(ws + O_SRC);
    int* dstI   = (int*)(ws + O_DST);
    int* deg    = (int*)(ws + O_DEG);
    int* cursor = (int*)(ws + O_CUR);
    int* startA = (int*)(ws + O_START);
    int* srcS   = (int*)(ws + O_SRCS);
    int* dstS   = (int*)(ws + O_DSTS);
    int* orig   = (int*)(ws + O_ORIG);
    float* relT = (float*)(ws + O_RELT);
    float* Q1   = (float*)(ws + O_Q1);
    unsigned short* K1b  = (unsigned short*)(ws + O_K1);
    unsigned short* V1b  = (unsigned short*)(ws + O_V1);
    unsigned short* S1mb = (unsigned short*)(ws + O_S1M);
    unsigned short* e2p  = (unsigned short*)(ws + O_E2P);
    float* num1 = (float*)(ws + O_NUM1);   // becomes h in-place
    float* s1   = (float*)(ws + O_S1S);
    float* num2 = (float*)(ws + O_NUM2);
    float* s2   = (float*)(ws + O_S2S);
    float* Q2   = (float*)(ws + O_Q2);
    float* K2m  = (float*)(ws + O_K2);
    float* V2m  = (float*)(ws + O_V2);
    float* S2m  = (float*)(ws + O_S2M);

    hipMemsetAsync(ws + O_DEG, 0, 200000, stream);
    hipMemsetAsync(ws + O_NUM1, 0, ZERO_BYTES, stream);

    k_detect<<<1, 64, 0, stream>>>((const unsigned int*)ei, flag);
    k_convert<<<(NE + 255) / 256, 256, 0, stream>>>(ei, flag, srcI, dstI);
    k_hist<<<(NE + 255) / 256, 256, 0, stream>>>(dstI, deg);
    k_scan<<<1, 256, 0, stream>>>(deg, startA, cursor);
    k_scatter<<<(NE + 255) / 256, 256, 0, stream>>>(srcI, dstI, lu, tE, cursor,
                                                    srcS, dstS, orig, relT);
    k_gemm1<<<dim3((NN + 63) / 64, 16), 256, 0, stream>>>(
        x, Wq1, Wk1, Wv1, Ws1, bq1, bk1, bv1, bs1, Q1, K1b, V1b, S1mb);
    k_edge1s<<<NE / 32, 256, 0, stream>>>(
        srcS, dstS, orig, relT, msg, tw, tb, We1, We2, Q1, K1b, V1b, num1, s1, e2p);
    k_fin1<<<(NN * 256) / 256, 256, 0, stream>>>(num1, s1, S1mb);
    k_gemm2<<<(NN + 31) / 32, 256, 0, stream>>>(
        num1, Wq2, Wk2, Wv2, Ws2, bq2, bk2, bv2, bs2, Q2, K2m, V2m, S2m);
    k_edge2s<<<NE / 32, 256, 0, stream>>>(srcS, dstS, e2p, Q2, K2m, V2m, num2, s2);
    k_fin2<<<(NN * 32) / 256, 256, 0, stream>>>(num2, s2, S2m, out);
}

// Round 3
// 1236.975 us; speedup vs baseline: 5.0817x; 1.1144x over previous
//
#include <hip/hip_runtime.h>
#include <math.h>

#define NN 50000
#define NE 400000
#define RSQRT32 0.17677669529663687f

// ---------------- workspace layout (bytes) ----------------
#define O_FLAG  0ULL
#define O_SRCI  256ULL                         // E*4 (unsorted, dead after scatter)
#define O_DSTI  (O_SRCI + 1600000ULL)          // E*4 (dead after scatter) -> s1 alias
#define O_DEG   (O_DSTI + 1600000ULL)          // N*4
#define O_CUR   (O_DEG + 200192ULL)            // N*4 (dead after scatter) -> s2 alias
#define O_START (O_CUR + 200192ULL)            // (N+1)*4
#define O_SRCS  (O_START + 200704ULL)          // E*4
#define O_DSTS  (O_SRCS + 1600000ULL)          // E*4
#define O_ORIG  (O_DSTS + 1600000ULL)          // E*4
#define O_RELT  (O_ORIG + 1600000ULL)          // E*4
#define O_Q1    (O_RELT + 1600000ULL)          // N*256*2 bf16; later numv1(w/K1), then Q2/K2/V2/S2m fp32
#define O_K1    (O_Q1 + 25600000ULL)           // N*256*2 bf16; later G2 fp32
#define O_V1    (O_K1 + 25600000ULL)           // N*256*2 bf16; later h bf16
#define O_S1M   (O_V1 + 25600000ULL)           // N*256*2 bf16; later A2 fp32
#define O_G1    (O_S1M + 25600000ULL)          // N*1024*2 bf16; later A1 bf16; later numv2 fp32
#define O_P1    (O_G1 + 102400000ULL)          // E*8*4 fp32
#define WS_TOTAL (O_P1 + 12800000ULL)
// aliases
#define O_NUMV1 O_Q1                           // N*256*4 fp32 (spans Q1+K1)
#define O_S1    O_DSTI                         // N*8*4
#define O_A1    O_G1                           // N*1024*2 bf16
#define O_H     O_V1                           // N*256*2 bf16
#define O_Q2    O_Q1                           // N*32*4 fp32
#define O_K2    (O_Q1 + 6400000ULL)
#define O_V2    (O_Q1 + 12800000ULL)
#define O_S2M   (O_Q1 + 19200000ULL)
#define O_G2    O_K1                           // N*128*4 fp32
#define O_A2    O_S1M                          // N*128*4 fp32
#define O_NUMV2 O_G1                           // N*32*4 fp32
#define O_S2    O_CUR                          // N*4

__device__ __forceinline__ unsigned short f2bf(float f) {
    unsigned int u = __float_as_uint(f);
    unsigned int r = (u + 0x7fffu + ((u >> 16) & 1u)) >> 16;
    return (unsigned short)r;
}
__device__ __forceinline__ float bf2f(unsigned short u) {
    return __uint_as_float(((unsigned int)u) << 16);
}
__device__ __forceinline__ float4 ld_bf16x4(const unsigned short* p) {
    const ushort4 u = *(const ushort4*)p;
    float4 r;
    r.x = bf2f(u.x); r.y = bf2f(u.y); r.z = bf2f(u.z); r.w = bf2f(u.w);
    return r;
}
__device__ __forceinline__ ushort4 st_bf16x4(float a, float b, float c, float d) {
    ushort4 u; u.x = f2bf(a); u.y = f2bf(b); u.z = f2bf(c); u.w = f2bf(d);
    return u;
}

// ---------------- index dtype detect + convert ----------------
__global__ void k_detect(const unsigned int* ei, int* flag) {
    if (threadIdx.x == 0) {
        int is64 = 1;
        for (int i = 0; i < 64; ++i)
            if (ei[2 * i + 1] != 0u) { is64 = 0; break; }
        *flag = is64;
    }
}

__global__ void k_convert(const void* ei, const int* flag, int* srcI, int* dstI) {
    int i = blockIdx.x * 256 + threadIdx.x;
    if (i >= NE) return;
    if (*flag) {
        const long long* p = (const long long*)ei;
        srcI[i] = (int)p[i];
        dstI[i] = (int)p[NE + i];
    } else {
        const int* p = (const int*)ei;
        srcI[i] = p[i];
        dstI[i] = p[NE + i];
    }
}

// ---------------- counting sort by dst ----------------
__global__ void k_hist(const int* __restrict__ dstI, int* __restrict__ deg) {
    int i = blockIdx.x * 256 + threadIdx.x;
    if (i < NE) atomicAdd(&deg[dstI[i]], 1);
}

#define NCHUNK 196  // ceil(50000/256)
__global__ void k_scan(const int* __restrict__ deg, int* __restrict__ start,
                       int* __restrict__ cursor) {
    __shared__ int sums[256];
    const int t = threadIdx.x;
    const int c0 = t * NCHUNK;
    int s = 0;
    for (int i = 0; i < NCHUNK; ++i) { int g = c0 + i; if (g < NN) s += deg[g]; }
    sums[t] = s;
    __syncthreads();
    for (int off = 1; off < 256; off <<= 1) {
        int v = (t >= off) ? sums[t - off] : 0;
        __syncthreads();
        sums[t] += v;
        __syncthreads();
    }
    int run = sums[t] - s;
    for (int i = 0; i < NCHUNK; ++i) {
        int g = c0 + i;
        if (g < NN) { start[g] = run; cursor[g] = run; run += deg[g]; }
        else if (g == NN) start[NN] = run;
    }
}

__global__ void k_scatter(const int* __restrict__ srcI, const int* __restrict__ dstI,
                          const float* __restrict__ lu, const float* __restrict__ tE,
                          int* __restrict__ cursor,
                          int* __restrict__ srcS, int* __restrict__ dstS,
                          int* __restrict__ orig, float* __restrict__ relT) {
    int i = blockIdx.x * 256 + threadIdx.x;
    if (i >= NE) return;
    const int d = dstI[i];
    const int s = srcI[i];
    const int pos = atomicAdd(&cursor[d], 1);
    srcS[pos] = s;
    dstS[pos] = d;
    orig[pos] = i;
    relT[pos] = lu[s] - tE[i];
}

// ---------------- node GEMM layer 1: x(50000x128) @ 4x(128x256), bf16 out ------
__global__ __launch_bounds__(256) void k_gemm1(
    const float* __restrict__ x,
    const float* __restrict__ B0, const float* __restrict__ B1,
    const float* __restrict__ B2, const float* __restrict__ B3,
    const float* __restrict__ c0, const float* __restrict__ c1,
    const float* __restrict__ c2, const float* __restrict__ c3,
    unsigned short* __restrict__ Q1b, unsigned short* __restrict__ K1b,
    unsigned short* __restrict__ V1b, unsigned short* __restrict__ S1mb)
{
    __shared__ float As[64 * 132];
    __shared__ float Bs[128 * 68];
    const int t = threadIdx.x;
    const int row0 = blockIdx.x * 64;
    const int by = blockIdx.y;
    const int part = by >> 2;
    const int pcol0 = (by & 3) * 64;
    const float* Bp = part == 0 ? B0 : part == 1 ? B1 : part == 2 ? B2 : B3;
    const float* bp = part == 0 ? c0 : part == 1 ? c1 : part == 2 ? c2 : c3;
    unsigned short* Ob = part == 0 ? Q1b : part == 1 ? K1b : part == 2 ? V1b : S1mb;

    {
        const int r = t >> 5;
        const int c = (t & 31) * 4;
        #pragma unroll
        for (int i = 0; i < 8; ++i) {
            const int rr = r + i * 8;
            const int gr = row0 + rr;
            float4 v = make_float4(0.f, 0.f, 0.f, 0.f);
            if (gr < NN) v = *(const float4*)(x + (size_t)gr * 128 + c);
            *(float4*)(As + rr * 132 + c) = v;
        }
    }
    {
        const int r = t >> 4;
        const int c = (t & 15) * 4;
        #pragma unroll
        for (int i = 0; i < 8; ++i) {
            const int rr = r + i * 16;
            float4 v = *(const float4*)(Bp + (size_t)rr * 256 + pcol0 + c);
            *(float4*)(Bs + rr * 68 + c) = v;
        }
    }
    __syncthreads();
    const int ty = t >> 4, tx = t & 15;
    float acc[4][4] = {};
    #pragma unroll 4
    for (int k = 0; k < 128; k += 4) {
        float4 a4[4], bv[4];
        #pragma unroll
        for (int i = 0; i < 4; ++i) a4[i] = *(const float4*)(As + (4 * ty + i) * 132 + k);
        #pragma unroll
        for (int kk = 0; kk < 4; ++kk) bv[kk] = *(const float4*)(Bs + (k + kk) * 68 + 4 * tx);
        #pragma unroll
        for (int i = 0; i < 4; ++i) {
            const float* ap = (const float*)&a4[i];
            #pragma unroll
            for (int kk = 0; kk < 4; ++kk) {
                const float av = ap[kk];
                acc[i][0] += av * bv[kk].x;
                acc[i][1] += av * bv[kk].y;
                acc[i][2] += av * bv[kk].z;
                acc[i][3] += av * bv[kk].w;
            }
        }
    }
    const int gc = pcol0 + tx * 4;
    const float4 bias = *(const float4*)(bp + gc);
    #pragma unroll
    for (int i = 0; i < 4; ++i) {
        const int gr = row0 + 4 * ty + i;
        if (gr < NN) {
            *(ushort4*)(Ob + (size_t)gr * 256 + gc) =
                st_bf16x4(acc[i][0] + bias.x, acc[i][1] + bias.y,
                          acc[i][2] + bias.z, acc[i][3] + bias.w);
        }
    }
}

// ---------------- G1: g1[n][h][k] = sum_c Q1[n][h*32+c] * We1[k][h*32+c] -------
__global__ __launch_bounds__(256) void k_g1(
    const unsigned short* __restrict__ Q1b, const float* __restrict__ We1,
    unsigned short* __restrict__ G1b)
{
    __shared__ float Qs[64][36];
    __shared__ float Ws[128][36];
    const int t = threadIdx.x;
    const int n0 = blockIdx.x * 64;
    const int h = blockIdx.y;
    {
        const int n = t >> 2, c8 = (t & 3) * 8;
        float4 v0 = make_float4(0.f,0.f,0.f,0.f), v1 = v0;
        if (n0 + n < NN) {
            v0 = ld_bf16x4(Q1b + (size_t)(n0 + n) * 256 + h * 32 + c8);
            v1 = ld_bf16x4(Q1b + (size_t)(n0 + n) * 256 + h * 32 + c8 + 4);
        }
        *(float4*)(&Qs[n][c8]) = v0;
        *(float4*)(&Qs[n][c8 + 4]) = v1;
    }
    {
        const int k = t >> 1, c16 = (t & 1) * 16;
        #pragma unroll
        for (int i = 0; i < 4; ++i)
            *(float4*)(&Ws[k][c16 + 4 * i]) =
                *(const float4*)(We1 + (size_t)k * 256 + h * 32 + c16 + 4 * i);
    }
    __syncthreads();
    const int tx = t & 15, ty = t >> 4;
    const int k8 = tx * 8, n4 = ty * 4;
    float acc[4][8] = {};
    #pragma unroll 8
    for (int c = 0; c < 32; ++c) {
        float a[4], b[8];
        #pragma unroll
        for (int i = 0; i < 4; ++i) a[i] = Qs[n4 + i][c];
        #pragma unroll
        for (int j = 0; j < 8; ++j) b[j] = Ws[k8 + j][c];
        #pragma unroll
        for (int i = 0; i < 4; ++i)
            #pragma unroll
            for (int j = 0; j < 8; ++j)
                acc[i][j] += a[i] * b[j];
    }
    #pragma unroll
    for (int i = 0; i < 4; ++i) {
        const int gn = n0 + n4 + i;
        if (gn < NN) {
            unsigned short* gp = G1b + (size_t)gn * 1024 + h * 128 + k8;
            *(ushort4*)(gp)     = st_bf16x4(acc[i][0], acc[i][1], acc[i][2], acc[i][3]);
            *(ushort4*)(gp + 4) = st_bf16x4(acc[i][4], acc[i][5], acc[i][6], acc[i][7]);
        }
    }
}

// ---------------- G2: g2[n][k] = sum_c Q2[n][c] * We2[k][c] --------------------
__global__ __launch_bounds__(256) void k_g2(
    const float* __restrict__ Q2, const float* __restrict__ We2,
    float* __restrict__ G2)
{
    __shared__ float Qs[64][36];
    __shared__ float Ws[128][36];
    const int t = threadIdx.x;
    const int n0 = blockIdx.x * 64;
    {
        const int n = t >> 2, c8 = (t & 3) * 8;
        float4 v0 = make_float4(0.f,0.f,0.f,0.f), v1 = v0;
        if (n0 + n < NN) {
            v0 = *(const float4*)(Q2 + (size_t)(n0 + n) * 32 + c8);
            v1 = *(const float4*)(Q2 + (size_t)(n0 + n) * 32 + c8 + 4);
        }
        *(float4*)(&Qs[n][c8]) = v0;
        *(float4*)(&Qs[n][c8 + 4]) = v1;
    }
    {
        const int k = t >> 1, c16 = (t & 1) * 16;
        #pragma unroll
        for (int i = 0; i < 4; ++i)
            *(float4*)(&Ws[k][c16 + 4 * i]) =
                *(const float4*)(We2 + (size_t)k * 32 + c16 + 4 * i);
    }
    __syncthreads();
    const int tx = t & 15, ty = t >> 4;
    const int k8 = tx * 8, n4 = ty * 4;
    float acc[4][8] = {};
    #pragma unroll 8
    for (int c = 0; c < 32; ++c) {
        float a[4], b[8];
        #pragma unroll
        for (int i = 0; i < 4; ++i) a[i] = Qs[n4 + i][c];
        #pragma unroll
        for (int j = 0; j < 8; ++j) b[j] = Ws[k8 + j][c];
        #pragma unroll
        for (int i = 0; i < 4; ++i)
            #pragma unroll
            for (int j = 0; j < 8; ++j)
                acc[i][j] += a[i] * b[j];
    }
    #pragma unroll
    for (int i = 0; i < 4; ++i) {
        const int gn = n0 + n4 + i;
        if (gn < NN) {
            float* gp = G2 + (size_t)gn * 128 + k8;
            *(float4*)(gp)     = make_float4(acc[i][0], acc[i][1], acc[i][2], acc[i][3]);
            *(float4*)(gp + 4) = make_float4(acc[i][4], acc[i][5], acc[i][6], acc[i][7]);
        }
    }
}

// ---------------- p-compute layer 1: p1[e][h] -------------------------
// 32 edges/block; attr staged in LDS; logit = q.k + attr.g1[dst,h]
__global__ __launch_bounds__(256) void k_pA1(
    const int* __restrict__ srcS, const int* __restrict__ dstS,
    const int* __restrict__ orig, const float* __restrict__ relT,
    const float* __restrict__ msg, const float* __restrict__ tw,
    const float* __restrict__ tb,
    const unsigned short* __restrict__ Q1b, const unsigned short* __restrict__ K1b,
    const unsigned short* __restrict__ G1b,
    float* __restrict__ p1)
{
    __shared__ float attrf[32][132];
    const int t = threadIdx.x;
    const int e0 = blockIdx.x * 32;

    { // stage attr
        const int j = t >> 3, seg = t & 7;
        const int eg = e0 + j;
        if (seg < 4) {
            const float rt = relT[eg];
            const int k0 = seg * 16;
            #pragma unroll
            for (int i = 0; i < 16; ++i) {
                const int k = k0 + i;
                attrf[j][k] = __cosf(rt * tw[k] + tb[k]);
            }
        } else {
            const int oe = orig[eg];
            const int m0 = (seg - 4) * 16;
            #pragma unroll
            for (int i = 0; i < 16; i += 4)
                *(float4*)(&attrf[j][64 + m0 + i]) =
                    *(const float4*)(msg + (size_t)oe * 64 + m0 + i);
        }
    }
    __syncthreads();

    const int j = t >> 3, h = t & 7;
    const int e = e0 + j;
    const int d = dstS[e], s = srcS[e];
    const unsigned short* qp = Q1b + (size_t)d * 256 + h * 32;
    const unsigned short* kp = K1b + (size_t)s * 256 + h * 32;
    const unsigned short* gp = G1b + (size_t)d * 1024 + h * 128;
    float dot = 0.f;
    #pragma unroll
    for (int c = 0; c < 32; c += 4) {
        const float4 q4 = ld_bf16x4(qp + c);
        const float4 k4 = ld_bf16x4(kp + c);
        dot += q4.x * k4.x + q4.y * k4.y + q4.z * k4.z + q4.w * k4.w;
    }
    #pragma unroll 8
    for (int kk = 0; kk < 128; kk += 4) {
        const float4 g4 = ld_bf16x4(gp + kk);
        const float4 a4 = *(const float4*)(&attrf[j][kk]);
        dot += a4.x * g4.x + a4.y * g4.y + a4.z * g4.z + a4.w * g4.w;
    }
    p1[(size_t)e * 8 + h] = __expf(fminf(dot * RSQRT32, 80.f));
}

// ---------------- aggregate layer 1 (dst-centric, no atomics) ------------------
// block = 8 dsts x 32 lanes. Accumulates numv1[256], A1[8][128], s1[8] per dst.
__global__ __launch_bounds__(256) void k_aggB1(
    const int* __restrict__ startA, const int* __restrict__ srcS,
    const int* __restrict__ orig, const float* __restrict__ relT,
    const float* __restrict__ msg, const float* __restrict__ tw,
    const float* __restrict__ tb,
    const float* __restrict__ p1, const unsigned short* __restrict__ V1b,
    unsigned short* __restrict__ A1b, float* __restrict__ numv1,
    float* __restrict__ s1)
{
    const int t = threadIdx.x;
    const int g = t >> 5, l = t & 31;
    const int d = blockIdx.x * 8 + g;
    const int eb = startA[d], ee = startA[d + 1];
    const int hl = l >> 2, cl0 = (l & 3) * 8;

    float4 twl = make_float4(0.f,0.f,0.f,0.f), tbl = twl;
    if (l < 16) {
        twl = *(const float4*)(tw + l * 4);
        tbl = *(const float4*)(tb + l * 4);
    }
    float a1acc[8][4] = {};
    float nv[8] = {};
    float sacc = 0.f;

    for (int e = eb; e < ee; ++e) {
        const int s = srcS[e];
        const float4 p03 = *(const float4*)(p1 + (size_t)e * 8);
        const float4 p47 = *(const float4*)(p1 + (size_t)e * 8 + 4);
        float a[4];
        if (l < 16) {
            const float rt = relT[e];
            a[0] = __cosf(rt * twl.x + tbl.x);
            a[1] = __cosf(rt * twl.y + tbl.y);
            a[2] = __cosf(rt * twl.z + tbl.z);
            a[3] = __cosf(rt * twl.w + tbl.w);
        } else {
            const int oe = orig[e];
            const float4 m4 = *(const float4*)(msg + (size_t)oe * 64 + (l - 16) * 4);
            a[0] = m4.x; a[1] = m4.y; a[2] = m4.z; a[3] = m4.w;
        }
        #pragma unroll
        for (int i = 0; i < 4; ++i) {
            a1acc[0][i] += p03.x * a[i];
            a1acc[1][i] += p03.y * a[i];
            a1acc[2][i] += p03.z * a[i];
            a1acc[3][i] += p03.w * a[i];
            a1acc[4][i] += p47.x * a[i];
            a1acc[5][i] += p47.y * a[i];
            a1acc[6][i] += p47.z * a[i];
            a1acc[7][i] += p47.w * a[i];
        }
        const float pv = p1[(size_t)e * 8 + hl];
        const unsigned short* vp = V1b + (size_t)s * 256 + hl * 32 + cl0;
        const float4 v0 = ld_bf16x4(vp);
        const float4 v1 = ld_bf16x4(vp + 4);
        nv[0] += pv * v0.x; nv[1] += pv * v0.y; nv[2] += pv * v0.z; nv[3] += pv * v0.w;
        nv[4] += pv * v1.x; nv[5] += pv * v1.y; nv[6] += pv * v1.z; nv[7] += pv * v1.w;
        if (l < 8) sacc += p1[(size_t)e * 8 + l];
    }
    #pragma unroll
    for (int h = 0; h < 8; ++h)
        *(ushort4*)(A1b + (size_t)d * 1024 + h * 128 + l * 4) =
            st_bf16x4(a1acc[h][0], a1acc[h][1], a1acc[h][2], a1acc[h][3]);
    float* np = numv1 + (size_t)d * 256 + hl * 32 + cl0;
    *(float4*)(np)     = make_float4(nv[0], nv[1], nv[2], nv[3]);
    *(float4*)(np + 4) = make_float4(nv[4], nv[5], nv[6], nv[7]);
    if (l < 8) s1[(size_t)d * 8 + l] = sacc;
}

// ---------------- fold layer 1: h = relu((numv1 + A1@We1)/s1 + skip) -----------
__global__ __launch_bounds__(256) void k_foldC1(
    const unsigned short* __restrict__ A1b, const float* __restrict__ We1,
    const float* __restrict__ numv1, const float* __restrict__ s1,
    const unsigned short* __restrict__ S1mb, unsigned short* __restrict__ hb)
{
    __shared__ float Ws[128][36];
    const int t = threadIdx.x;
    const int h = blockIdx.y;
    {
        const int k = t >> 1, c16 = (t & 1) * 16;
        #pragma unroll
        for (int i = 0; i < 4; ++i)
            *(float4*)(&Ws[k][c16 + 4 * i]) =
                *(const float4*)(We1 + (size_t)k * 256 + h * 32 + c16 + 4 * i);
    }
    __syncthreads();
    const int n = blockIdx.x * 32 + (t >> 3);
    const int cg = t & 7;
    if (n >= NN) return;
    const unsigned short* ap = A1b + (size_t)n * 1024 + h * 128;
    float acc[4] = {};
    #pragma unroll 8
    for (int k = 0; k < 128; k += 4) {
        const float4 a4 = ld_bf16x4(ap + k);
        const float af[4] = {a4.x, a4.y, a4.z, a4.w};
        #pragma unroll
        for (int i = 0; i < 4; ++i)
            #pragma unroll
            for (int j = 0; j < 4; ++j)
                acc[j] += af[i] * Ws[k + i][cg * 4 + j];
    }
    const float s = s1[(size_t)n * 8 + h] + 1e-16f;
    const float4 nv = *(const float4*)(numv1 + (size_t)n * 256 + h * 32 + cg * 4);
    const float4 sk = ld_bf16x4(S1mb + (size_t)n * 256 + h * 32 + cg * 4);
    float o0 = (acc[0] + nv.x) / s + sk.x;
    float o1 = (acc[1] + nv.y) / s + sk.y;
    float o2 = (acc[2] + nv.z) / s + sk.z;
    float o3 = (acc[3] + nv.w) / s + sk.w;
    o0 = o0 > 0.f ? o0 : 0.f; o1 = o1 > 0.f ? o1 : 0.f;
    o2 = o2 > 0.f ? o2 : 0.f; o3 = o3 > 0.f ? o3 : 0.f;
    *(ushort4*)(hb + (size_t)n * 256 + h * 32 + cg * 4) = st_bf16x4(o0, o1, o2, o3);
}

// ---------------- node GEMM layer 2: h(bf16, 50000x256) @ 4x(256x32) -----------
__global__ __launch_bounds__(256) void k_gemm2(
    const unsigned short* __restrict__ hb,
    const float* __restrict__ B0, const float* __restrict__ B1,
    const float* __restrict__ B2, const float* __restrict__ B3,
    const float* __restrict__ c0, const float* __restrict__ c1,
    const float* __restrict__ c2, const float* __restrict__ c3,
    float* __restrict__ O0, float* __restrict__ O1,
    float* __restrict__ O2, float* __restrict__ O3)
{
    __shared__ float As[32 * 68];
    __shared__ float Bs[64 * 132];
    const int t = threadIdx.x;
    const int row0 = blockIdx.x * 32;
    const int ty = t >> 5, tx = t & 31;
    float acc[4][4] = {};
    for (int k0 = 0; k0 < 256; k0 += 64) {
        if (k0) __syncthreads();
        {
            const int r = t >> 4, c = (t & 15) * 4;
            #pragma unroll
            for (int i = 0; i < 2; ++i) {
                const int rr = r + i * 16;
                const int gr = row0 + rr;
                float4 v = make_float4(0.f, 0.f, 0.f, 0.f);
                if (gr < NN) v = ld_bf16x4(hb + (size_t)gr * 256 + k0 + c);
                *(float4*)(As + rr * 68 + c) = v;
            }
        }
        {
            const int r = t >> 5, c = (t & 31) * 4;
            const int part = c >> 5, pc = c & 31;
            const float* bsrc = part == 0 ? B0 : part == 1 ? B1 : part == 2 ? B2 : B3;
            #pragma unroll
            for (int i = 0; i < 8; ++i) {
                const int rr = r + i * 8;
                float4 v = *(const float4*)(bsrc + (size_t)(k0 + rr) * 32 + pc);
                *(float4*)(Bs + rr * 132 + c) = v;
            }
        }
        __syncthreads();
        #pragma unroll 4
        for (int k = 0; k < 64; k += 4) {
            float4 a4[4], bv[4];
            #pragma unroll
            for (int i = 0; i < 4; ++i) a4[i] = *(const float4*)(As + (4 * ty + i) * 68 + k);
            #pragma unroll
            for (int kk = 0; kk < 4; ++kk) bv[kk] = *(const float4*)(Bs + (k + kk) * 132 + 4 * tx);
            #pragma unroll
            for (int i = 0; i < 4; ++i) {
                const float* ap = (const float*)&a4[i];
                #pragma unroll
                for (int kk = 0; kk < 4; ++kk) {
                    const float av = ap[kk];
                    acc[i][0] += av * bv[kk].x;
                    acc[i][1] += av * bv[kk].y;
                    acc[i][2] += av * bv[kk].z;
                    acc[i][3] += av * bv[kk].w;
                }
            }
        }
    }
    const int part = tx >> 3, pc = (tx & 7) * 4;
    const float* bb = part == 0 ? c0 : part == 1 ? c1 : part == 2 ? c2 : c3;
    float* Op = part == 0 ? O0 : part == 1 ? O1 : part == 2 ? O2 : O3;
    const float4 bias = *(const float4*)(bb + pc);
    #pragma unroll
    for (int i = 0; i < 4; ++i) {
        const int gr = row0 + 4 * ty + i;
        if (gr < NN) {
            float4 o = make_float4(acc[i][0] + bias.x, acc[i][1] + bias.y,
                                   acc[i][2] + bias.z, acc[i][3] + bias.w);
            *(float4*)(Op + (size_t)gr * 32 + pc) = o;
        }
    }
}

// ---------------- layer 2 fused p + aggregate (dst-centric) --------------------
__global__ __launch_bounds__(256) void k_aggB2(
    const int* __restrict__ startA, const int* __restrict__ srcS,
    const int* __restrict__ orig, const float* __restrict__ relT,
    const float* __restrict__ msg, const float* __restrict__ tw,
    const float* __restrict__ tb,
    const float* __restrict__ Q2, const float* __restrict__ K2,
    const float* __restrict__ V2, const float* __restrict__ G2,
    float* __restrict__ A2, float* __restrict__ numv2, float* __restrict__ s2)
{
    const int t = threadIdx.x;
    const int g = t >> 5, l = t & 31;
    const int d = blockIdx.x * 8 + g;
    const int eb = startA[d], ee = startA[d + 1];

    const float q2l = Q2[(size_t)d * 32 + l];
    const float4 g2l = *(const float4*)(G2 + (size_t)d * 128 + l * 4);
    float4 twl = make_float4(0.f,0.f,0.f,0.f), tbl = twl;
    if (l < 16) {
        twl = *(const float4*)(tw + l * 4);
        tbl = *(const float4*)(tb + l * 4);
    }
    float acc2[4] = {};
    float nvacc = 0.f, sacc = 0.f;

    for (int e = eb; e < ee; ++e) {
        const int s = srcS[e];
        float a[4];
        if (l < 16) {
            const float rt = relT[e];
            a[0] = __cosf(rt * twl.x + tbl.x);
            a[1] = __cosf(rt * twl.y + tbl.y);
            a[2] = __cosf(rt * twl.z + tbl.z);
            a[3] = __cosf(rt * twl.w + tbl.w);
        } else {
            const int oe = orig[e];
            const float4 m4 = *(const float4*)(msg + (size_t)oe * 64 + (l - 16) * 4);
            a[0] = m4.x; a[1] = m4.y; a[2] = m4.z; a[3] = m4.w;
        }
        float part = q2l * K2[(size_t)s * 32 + l];
        part += a[0] * g2l.x + a[1] * g2l.y + a[2] * g2l.z + a[3] * g2l.w;
        part += __shfl_xor(part, 1);
        part += __shfl_xor(part, 2);
        part += __shfl_xor(part, 4);
        part += __shfl_xor(part, 8);
        part += __shfl_xor(part, 16);
        const float p = __expf(fminf(part * RSQRT32, 80.f));
        acc2[0] += p * a[0]; acc2[1] += p * a[1];
        acc2[2] += p * a[2]; acc2[3] += p * a[3];
        nvacc += p * V2[(size_t)s * 32 + l];
        sacc += p;
    }
    *(float4*)(A2 + (size_t)d * 128 + l * 4) =
        make_float4(acc2[0], acc2[1], acc2[2], acc2[3]);
    numv2[(size_t)d * 32 + l] = nvacc;
    if (l == 0) s2[d] = sacc;
}

// ---------------- fold layer 2: out = relu((numv2 + A2@We2)/s2 + skip2) --------
__global__ __launch_bounds__(256) void k_foldC2(
    const float* __restrict__ A2, const float* __restrict__ We2,
    const float* __restrict__ numv2, const float* __restrict__ s2,
    const float* __restrict__ S2m, float* __restrict__ out)
{
    __shared__ float Ws[128][36];
    const int t = threadIdx.x;
    {
        const int k = t >> 1, c16 = (t & 1) * 16;
        #pragma unroll
        for (int i = 0; i < 4; ++i)
            *(float4*)(&Ws[k][c16 + 4 * i]) =
                *(const float4*)(We2 + (size_t)k * 32 + c16 + 4 * i);
    }
    __syncthreads();
    const int n = blockIdx.x * 8 + (t >> 5);
    const int c = t & 31;
    const float* ap = A2 + (size_t)n * 128;
    float acc = 0.f;
    #pragma unroll 8
    for (int k = 0; k < 128; k += 4) {
        const float4 a4 = *(const float4*)(ap + k);
        acc += a4.x * Ws[k][c] + a4.y * Ws[k + 1][c] +
               a4.z * Ws[k + 2][c] + a4.w * Ws[k + 3][c];
    }
    const float s = s2[n] + 1e-16f;
    float v = (numv2[(size_t)n * 32 + c] + acc) / s + S2m[(size_t)n * 32 + c];
    out[(size_t)n * 32 + c] = v > 0.f ? v : 0.f;
}

extern "C" void kernel_launch(void* const* d_in, const int* in_sizes, int n_in,
                              void* d_out, int out_size, void* d_ws, size_t ws_size,
                              hipStream_t stream) {
    const float* x   = (const float*)d_in[0];
    const float* lu  = (const float*)d_in[1];
    const void*  ei  = d_in[2];
    const float* tE  = (const float*)d_in[3];
    const float* msg = (const float*)d_in[4];
    const float* tw  = (const float*)d_in[5];
    const float* tb  = (const float*)d_in[6];
    const float* Wq1 = (const float*)d_in[7];  const float* bq1 = (const float*)d_in[8];
    const float* Wk1 = (const float*)d_in[9];  const float* bk1 = (const float*)d_in[10];
    const float* Wv1 = (const float*)d_in[11]; const float* bv1 = (const float*)d_in[12];
    const float* We1 = (const float*)d_in[13];
    const float* Ws1 = (const float*)d_in[14]; const float* bs1 = (const float*)d_in[15];
    const float* Wq2 = (const float*)d_in[16]; const float* bq2 = (const float*)d_in[17];
    const float* Wk2 = (const float*)d_in[18]; const float* bk2 = (const float*)d_in[19];
    const float* Wv2 = (const float*)d_in[20]; const float* bv2 = (const float*)d_in[21];
    const float* We2 = (const float*)d_in[22];
    const float* Ws2 = (const float*)d_in[23]; const float* bs2 = (const float*)d_in[24];
    float* out = (float*)d_out;
    char* ws = (char*)d_ws;

    if (ws_size < WS_TOTAL) return;

    int* flag   = (int*)(ws + O_FLAG);
    int* srcI   = (int*)(ws + O_SRCI);
    int* dstI   = (int*)(ws + O_DSTI);
    int* deg    = (int*)(ws + O_DEG);
    int* cursor = (int*)(ws + O_CUR);
    int* startA = (int*)(ws + O_START);
    int* srcS   = (int*)(ws + O_SRCS);
    int* dstS   = (int*)(ws + O_DSTS);
    int* orig   = (int*)(ws + O_ORIG);
    float* relT = (float*)(ws + O_RELT);
    unsigned short* Q1b  = (unsigned short*)(ws + O_Q1);
    unsigned short* K1b  = (unsigned short*)(ws + O_K1);
    unsigned short* V1b  = (unsigned short*)(ws + O_V1);
    unsigned short* S1mb = (unsigned short*)(ws + O_S1M);
    unsigned short* G1b  = (unsigned short*)(ws + O_G1);
    float* p1   = (float*)(ws + O_P1);
    unsigned short* A1b  = (unsigned short*)(ws + O_A1);
    float* numv1 = (float*)(ws + O_NUMV1);
    float* s1    = (float*)(ws + O_S1);
    unsigned short* hb = (unsigned short*)(ws + O_H);
    float* Q2   = (float*)(ws + O_Q2);
    float* K2m  = (float*)(ws + O_K2);
    float* V2m  = (float*)(ws + O_V2);
    float* S2m  = (float*)(ws + O_S2M);
    float* G2   = (float*)(ws + O_G2);
    float* A2   = (float*)(ws + O_A2);
    float* numv2 = (float*)(ws + O_NUMV2);
    float* s2   = (float*)(ws + O_S2);

    hipMemsetAsync(ws + O_DEG, 0, 200000, stream);

    k_detect<<<1, 64, 0, stream>>>((const unsigned int*)ei, flag);
    k_convert<<<(NE + 255) / 256, 256, 0, stream>>>(ei, flag, srcI, dstI);
    k_hist<<<(NE + 255) / 256, 256, 0, stream>>>(dstI, deg);
    k_scan<<<1, 256, 0, stream>>>(deg, startA, cursor);
    k_scatter<<<(NE + 255) / 256, 256, 0, stream>>>(srcI, dstI, lu, tE, cursor,
                                                    srcS, dstS, orig, relT);
    k_gemm1<<<dim3(782, 16), 256, 0, stream>>>(
        x, Wq1, Wk1, Wv1, Ws1, bq1, bk1, bv1, bs1, Q1b, K1b, V1b, S1mb);
    k_g1<<<dim3(782, 8), 256, 0, stream>>>(Q1b, We1, G1b);
    k_pA1<<<NE / 32, 256, 0, stream>>>(srcS, dstS, orig, relT, msg, tw, tb,
                                       Q1b, K1b, G1b, p1);
    k_aggB1<<<NN / 8, 256, 0, stream>>>(startA, srcS, orig, relT, msg, tw, tb,
                                        p1, V1b, A1b, numv1, s1);
    k_foldC1<<<dim3(1563, 8), 256, 0, stream>>>(A1b, We1, numv1, s1, S1mb, hb);
    k_gemm2<<<1563, 256, 0, stream>>>(
        hb, Wq2, Wk2, Wv2, Ws2, bq2, bk2, bv2, bs2, Q2, K2m, V2m, S2m);
    k_g2<<<782, 256, 0, stream>>>(Q2, We2, G2);
    k_aggB2<<<NN / 8, 256, 0, stream>>>(startA, srcS, orig, relT, msg, tw, tb,
                                        Q2, K2m, V2m, G2, A2, numv2, s2);
    k_foldC2<<<NN / 8, 256, 0, stream>>>(A2, We2, numv2, s2, S2m, out);
}

// Round 4
// 1002.745 us; speedup vs baseline: 6.2688x; 1.2336x over previous
//
#include <hip/hip_runtime.h>
#include <math.h>

#define NN 50000
#define NE 400000
#define RSQRT32 0.17677669529663687f

typedef __attribute__((ext_vector_type(8))) short bf16x8;
typedef __attribute__((ext_vector_type(4))) float f32x4;
#define MFMA_B16(a, b, c) __builtin_amdgcn_mfma_f32_16x16x32_bf16(a, b, c, 0, 0, 0)

// ---------------- workspace layout (bytes) ----------------
#define O_FLAG  0ULL
#define O_SRCI  256ULL                         // E*4
#define O_DSTI  (O_SRCI + 1600000ULL)          // E*4 -> s1 alias
#define O_DEG   (O_DSTI + 1600000ULL)          // N*4
#define O_CUR   (O_DEG + 200192ULL)            // N*4 -> s2 alias
#define O_START (O_CUR + 200192ULL)            // (N+1)*4
#define O_SRCS  (O_START + 200704ULL)          // E*4
#define O_DSTS  (O_SRCS + 1600000ULL)          // E*4
#define O_ORIG  (O_DSTS + 1600000ULL)          // E*4
#define O_RELT  (O_ORIG + 1600000ULL)          // E*4
#define O_Q1    (O_RELT + 1600000ULL)          // N*256*2 bf16; later numv1; later Q2/K2/V2/S2m fp32
#define O_K1    (O_Q1 + 25600000ULL)           // bf16; later G2 fp32
#define O_V1    (O_K1 + 25600000ULL)           // bf16; later h bf16
#define O_S1M   (O_V1 + 25600000ULL)           // bf16; later A2 fp32
#define O_G1    (O_S1M + 25600000ULL)          // N*1024*2 bf16; later A1 bf16; later numv2 fp32
#define O_P1    (O_G1 + 102400000ULL)          // E*8*4 fp32
#define O_WB1   (O_P1 + 12800000ULL)           // [4][256][128] bf16
#define O_WG1   (O_WB1 + 262144ULL)            // [8][128][32] bf16
#define O_WF1   (O_WG1 + 65536ULL)             // [8][32][128] bf16
#define O_WB2   (O_WF1 + 65536ULL)             // [128][256] bf16
#define WS_TOTAL (O_WB2 + 65536ULL)
// aliases
#define O_NUMV1 O_Q1                           // N*256*4 fp32 (spans Q1+K1)
#define O_S1    O_DSTI                         // N*8*4
#define O_A1    O_G1                           // N*1024*2 bf16
#define O_H     O_V1                           // N*256*2 bf16
#define O_Q2    O_Q1                           // N*32*4 fp32
#define O_K2    (O_Q1 + 6400000ULL)
#define O_V2    (O_Q1 + 12800000ULL)
#define O_S2M   (O_Q1 + 19200000ULL)
#define O_G2    O_K1                           // N*128*4 fp32
#define O_A2    O_S1M                          // N*128*4 fp32
#define O_NUMV2 O_G1                           // N*32*4 fp32
#define O_S2    O_CUR                          // N*4

__device__ __forceinline__ unsigned short f2bf(float f) {
    unsigned int u = __float_as_uint(f);
    unsigned int r = (u + 0x7fffu + ((u >> 16) & 1u)) >> 16;
    return (unsigned short)r;
}
__device__ __forceinline__ float bf2f(unsigned short u) {
    return __uint_as_float(((unsigned int)u) << 16);
}
__device__ __forceinline__ float4 ld_bf16x4(const unsigned short* p) {
    const ushort4 u = *(const ushort4*)p;
    float4 r;
    r.x = bf2f(u.x); r.y = bf2f(u.y); r.z = bf2f(u.z); r.w = bf2f(u.w);
    return r;
}
__device__ __forceinline__ ushort4 st_bf16x4(float a, float b, float c, float d) {
    ushort4 u; u.x = f2bf(a); u.y = f2bf(b); u.z = f2bf(c); u.w = f2bf(d);
    return u;
}

// ---------------- index dtype detect + convert ----------------
__global__ void k_detect(const unsigned int* ei, int* flag) {
    if (threadIdx.x == 0) {
        int is64 = 1;
        for (int i = 0; i < 64; ++i)
            if (ei[2 * i + 1] != 0u) { is64 = 0; break; }
        *flag = is64;
    }
}

__global__ void k_convert(const void* ei, const int* flag, int* srcI, int* dstI) {
    int i = blockIdx.x * 256 + threadIdx.x;
    if (i >= NE) return;
    if (*flag) {
        const long long* p = (const long long*)ei;
        srcI[i] = (int)p[i];
        dstI[i] = (int)p[NE + i];
    } else {
        const int* p = (const int*)ei;
        srcI[i] = p[i];
        dstI[i] = p[NE + i];
    }
}

// ---------------- counting sort by dst ----------------
__global__ void k_hist(const int* __restrict__ dstI, int* __restrict__ deg) {
    int i = blockIdx.x * 256 + threadIdx.x;
    if (i < NE) atomicAdd(&deg[dstI[i]], 1);
}

#define NCHUNK 196
__global__ void k_scan(const int* __restrict__ deg, int* __restrict__ start,
                       int* __restrict__ cursor) {
    __shared__ int sums[256];
    const int t = threadIdx.x;
    const int c0 = t * NCHUNK;
    int s = 0;
    for (int i = 0; i < NCHUNK; ++i) { int g = c0 + i; if (g < NN) s += deg[g]; }
    sums[t] = s;
    __syncthreads();
    for (int off = 1; off < 256; off <<= 1) {
        int v = (t >= off) ? sums[t - off] : 0;
        __syncthreads();
        sums[t] += v;
        __syncthreads();
    }
    int run = sums[t] - s;
    for (int i = 0; i < NCHUNK; ++i) {
        int g = c0 + i;
        if (g < NN) { start[g] = run; cursor[g] = run; run += deg[g]; }
        else if (g == NN) start[NN] = run;
    }
}

__global__ void k_scatter(const int* __restrict__ srcI, const int* __restrict__ dstI,
                          const float* __restrict__ lu, const float* __restrict__ tE,
                          int* __restrict__ cursor,
                          int* __restrict__ srcS, int* __restrict__ dstS,
                          int* __restrict__ orig, float* __restrict__ relT) {
    int i = blockIdx.x * 256 + threadIdx.x;
    if (i >= NE) return;
    const int d = dstI[i];
    const int s = srcI[i];
    const int pos = atomicAdd(&cursor[d], 1);
    srcS[pos] = s;
    dstS[pos] = d;
    orig[pos] = i;
    relT[pos] = lu[s] - tE[i];
}

// ---------------- weight prep: pack bf16 B^T forms ----------------
__global__ void k_prepw(
    const float* __restrict__ Wq1, const float* __restrict__ Wk1,
    const float* __restrict__ Wv1, const float* __restrict__ Ws1,
    const float* __restrict__ We1,
    const float* __restrict__ Wq2, const float* __restrict__ Wk2,
    const float* __restrict__ Wv2, const float* __restrict__ Ws2,
    unsigned short* __restrict__ WB1, unsigned short* __restrict__ WG1,
    unsigned short* __restrict__ WF1, unsigned short* __restrict__ WB2)
{
    const int i = blockIdx.x * 256 + threadIdx.x;
    if (i < 131072) {                       // WB1[part][n 256][k 128]
        const int part = i >> 15;
        const int rem = i & 32767;
        const int n = rem >> 7, k = rem & 127;
        const float* W = part == 0 ? Wq1 : part == 1 ? Wk1 : part == 2 ? Wv1 : Ws1;
        WB1[i] = f2bf(W[(size_t)k * 256 + n]);
    } else if (i < 163840) {                // WG1[h][ko 128][c 32]
        const int j = i - 131072;
        const int h = j >> 12, ko = (j >> 5) & 127, c = j & 31;
        WG1[j] = f2bf(We1[(size_t)ko * 256 + h * 32 + c]);
    } else if (i < 196608) {                // WF1[h][c 32][ko 128]
        const int j = i - 163840;
        const int h = j >> 12, c = (j >> 7) & 31, ko = j & 127;
        WF1[j] = f2bf(We1[(size_t)ko * 256 + h * 32 + c]);
    } else if (i < 229376) {                // WB2[col 128][k 256]
        const int j = i - 196608;
        const int col = j >> 8, k = j & 255;
        const int part = col >> 5, pc = col & 31;
        const float* W = part == 0 ? Wq2 : part == 1 ? Wk2 : part == 2 ? Wv2 : Ws2;
        WB2[j] = f2bf(W[(size_t)k * 32 + pc]);
    }
}

// ---------------- MFMA node GEMM layer 1: x @ 4x(128x256), bf16 out ------------
__global__ __launch_bounds__(256) void k_gemm1m(
    const float* __restrict__ x, const unsigned short* __restrict__ WB1,
    const float* __restrict__ c0, const float* __restrict__ c1,
    const float* __restrict__ c2, const float* __restrict__ c3,
    unsigned short* __restrict__ Q1b, unsigned short* __restrict__ K1b,
    unsigned short* __restrict__ V1b, unsigned short* __restrict__ S1mb)
{
    __shared__ unsigned short As[64 * 136];
    __shared__ unsigned short Bs[64 * 136];
    const int t = threadIdx.x;
    const int row0 = blockIdx.x * 64;
    const int by = blockIdx.y;
    const int part = by >> 2;
    const int pcol0 = (by & 3) * 64;
    const float* bp = part == 0 ? c0 : part == 1 ? c1 : part == 2 ? c2 : c3;
    unsigned short* Ob = part == 0 ? Q1b : part == 1 ? K1b : part == 2 ? V1b : S1mb;

    { // stage A (fp32 -> bf16)
        const int r = t >> 2, cc = (t & 3) * 32;
        const int gr = row0 + r;
        unsigned short* dst = As + r * 136 + cc;
        if (gr < NN) {
            const float4* xp = (const float4*)(x + (size_t)gr * 128 + cc);
            #pragma unroll
            for (int i = 0; i < 8; ++i) {
                const float4 v = xp[i];
                *(ushort4*)(dst + 4 * i) = st_bf16x4(v.x, v.y, v.z, v.w);
            }
        } else {
            const ushort4 z = {0, 0, 0, 0};
            #pragma unroll
            for (int i = 0; i < 8; ++i) *(ushort4*)(dst + 4 * i) = z;
        }
    }
    { // stage B^T (already bf16, K-contiguous)
        const int n = t >> 2, kk = (t & 3) * 32;
        const unsigned short* src = WB1 + ((size_t)part * 256 + pcol0 + n) * 128 + kk;
        unsigned short* dst = Bs + n * 136 + kk;
        #pragma unroll
        for (int i = 0; i < 4; ++i)
            *(bf16x8*)(dst + 8 * i) = *(const bf16x8*)(src + 8 * i);
    }
    __syncthreads();

    const int w = t >> 6, lane = t & 63, m = lane & 15, quad = lane >> 4;
    f32x4 acc[4];
    #pragma unroll
    for (int i = 0; i < 4; ++i) acc[i] = (f32x4){0.f, 0.f, 0.f, 0.f};
    #pragma unroll
    for (int kc = 0; kc < 4; ++kc) {
        const bf16x8 af = *(const bf16x8*)(As + (16 * w + m) * 136 + kc * 32 + quad * 8);
        #pragma unroll
        for (int ct = 0; ct < 4; ++ct) {
            const bf16x8 bf = *(const bf16x8*)(Bs + (16 * ct + m) * 136 + kc * 32 + quad * 8);
            acc[ct] = MFMA_B16(af, bf, acc[ct]);
        }
    }
    #pragma unroll
    for (int ct = 0; ct < 4; ++ct) {
        const int colp = pcol0 + ct * 16 + m;
        const float b = bp[colp];
        #pragma unroll
        for (int r = 0; r < 4; ++r) {
            const int gr = row0 + 16 * w + quad * 4 + r;
            if (gr < NN) Ob[(size_t)gr * 256 + colp] = f2bf(acc[ct][r] + b);
        }
    }
}

// ---------------- MFMA G1: g1[n][h][k] = sum_c Q1[n][h*32+c]*We1[k][h*32+c] ----
__global__ __launch_bounds__(256) void k_g1m(
    const unsigned short* __restrict__ Q1b, const unsigned short* __restrict__ WG1,
    unsigned short* __restrict__ G1b)
{
    __shared__ unsigned short As[64 * 40];
    __shared__ unsigned short Bs[128 * 40];
    const int t = threadIdx.x;
    const int n0 = blockIdx.x * 64;
    const int h = blockIdx.y;
    { // stage A: Q1 slice [64][32]
        const int n = t >> 2, c = (t & 3) * 8;
        const int gn = n0 + n;
        bf16x8 v = {};
        if (gn < NN) v = *(const bf16x8*)(Q1b + (size_t)gn * 256 + h * 32 + c);
        *(bf16x8*)(As + n * 40 + c) = v;
    }
    { // stage B^T: WG1[h] [128][32]
        const int ko = t >> 1, c = (t & 1) * 16;
        const unsigned short* src = WG1 + (size_t)h * 4096 + ko * 32 + c;
        *(bf16x8*)(Bs + ko * 40 + c) = *(const bf16x8*)(src);
        *(bf16x8*)(Bs + ko * 40 + c + 8) = *(const bf16x8*)(src + 8);
    }
    __syncthreads();

    const int w = t >> 6, lane = t & 63, m = lane & 15, quad = lane >> 4;
    f32x4 acc[8];
    #pragma unroll
    for (int i = 0; i < 8; ++i) acc[i] = (f32x4){0.f, 0.f, 0.f, 0.f};
    const bf16x8 af = *(const bf16x8*)(As + (16 * w + m) * 40 + quad * 8);
    #pragma unroll
    for (int ct = 0; ct < 8; ++ct) {
        const bf16x8 bf = *(const bf16x8*)(Bs + (16 * ct + m) * 40 + quad * 8);
        acc[ct] = MFMA_B16(af, bf, acc[ct]);
    }
    #pragma unroll
    for (int ct = 0; ct < 8; ++ct) {
        const int k = ct * 16 + m;
        #pragma unroll
        for (int r = 0; r < 4; ++r) {
            const int gn = n0 + 16 * w + quad * 4 + r;
            if (gn < NN) G1b[(size_t)gn * 1024 + h * 128 + k] = f2bf(acc[ct][r]);
        }
    }
}

// ---------------- G2: g2[n][k] = sum_c Q2[n][c] * We2[k][c] (scalar fp32) ------
__global__ __launch_bounds__(256) void k_g2(
    const float* __restrict__ Q2, const float* __restrict__ We2,
    float* __restrict__ G2)
{
    __shared__ float Qs[64][36];
    __shared__ float Ws[128][36];
    const int t = threadIdx.x;
    const int n0 = blockIdx.x * 64;
    {
        const int n = t >> 2, c8 = (t & 3) * 8;
        float4 v0 = make_float4(0.f,0.f,0.f,0.f), v1 = v0;
        if (n0 + n < NN) {
            v0 = *(const float4*)(Q2 + (size_t)(n0 + n) * 32 + c8);
            v1 = *(const float4*)(Q2 + (size_t)(n0 + n) * 32 + c8 + 4);
        }
        *(float4*)(&Qs[n][c8]) = v0;
        *(float4*)(&Qs[n][c8 + 4]) = v1;
    }
    {
        const int k = t >> 1, c16 = (t & 1) * 16;
        #pragma unroll
        for (int i = 0; i < 4; ++i)
            *(float4*)(&Ws[k][c16 + 4 * i]) =
                *(const float4*)(We2 + (size_t)k * 32 + c16 + 4 * i);
    }
    __syncthreads();
    const int tx = t & 15, ty = t >> 4;
    const int k8 = tx * 8, n4 = ty * 4;
    float acc[4][8] = {};
    #pragma unroll 8
    for (int c = 0; c < 32; ++c) {
        float a[4], b[8];
        #pragma unroll
        for (int i = 0; i < 4; ++i) a[i] = Qs[n4 + i][c];
        #pragma unroll
        for (int j = 0; j < 8; ++j) b[j] = Ws[k8 + j][c];
        #pragma unroll
        for (int i = 0; i < 4; ++i)
            #pragma unroll
            for (int j = 0; j < 8; ++j)
                acc[i][j] += a[i] * b[j];
    }
    #pragma unroll
    for (int i = 0; i < 4; ++i) {
        const int gn = n0 + n4 + i;
        if (gn < NN) {
            float* gp = G2 + (size_t)gn * 128 + k8;
            *(float4*)(gp)     = make_float4(acc[i][0], acc[i][1], acc[i][2], acc[i][3]);
            *(float4*)(gp + 4) = make_float4(acc[i][4], acc[i][5], acc[i][6], acc[i][7]);
        }
    }
}

// ---------------- p-compute layer 1 ----------------
__global__ __launch_bounds__(256) void k_pA1(
    const int* __restrict__ srcS, const int* __restrict__ dstS,
    const int* __restrict__ orig, const float* __restrict__ relT,
    const float* __restrict__ msg, const float* __restrict__ tw,
    const float* __restrict__ tb,
    const unsigned short* __restrict__ Q1b, const unsigned short* __restrict__ K1b,
    const unsigned short* __restrict__ G1b,
    float* __restrict__ p1)
{
    __shared__ float attrf[32][132];
    const int t = threadIdx.x;
    const int e0 = blockIdx.x * 32;

    {
        const int j = t >> 3, seg = t & 7;
        const int eg = e0 + j;
        if (seg < 4) {
            const float rt = relT[eg];
            const int k0 = seg * 16;
            #pragma unroll
            for (int i = 0; i < 16; ++i) {
                const int k = k0 + i;
                attrf[j][k] = __cosf(rt * tw[k] + tb[k]);
            }
        } else {
            const int oe = orig[eg];
            const int m0 = (seg - 4) * 16;
            #pragma unroll
            for (int i = 0; i < 16; i += 4)
                *(float4*)(&attrf[j][64 + m0 + i]) =
                    *(const float4*)(msg + (size_t)oe * 64 + m0 + i);
        }
    }
    __syncthreads();

    const int j = t >> 3, h = t & 7;
    const int e = e0 + j;
    const int d = dstS[e], s = srcS[e];
    const unsigned short* qp = Q1b + (size_t)d * 256 + h * 32;
    const unsigned short* kp = K1b + (size_t)s * 256 + h * 32;
    const unsigned short* gp = G1b + (size_t)d * 1024 + h * 128;
    float dot = 0.f;
    #pragma unroll
    for (int c = 0; c < 32; c += 4) {
        const float4 q4 = ld_bf16x4(qp + c);
        const float4 k4 = ld_bf16x4(kp + c);
        dot += q4.x * k4.x + q4.y * k4.y + q4.z * k4.z + q4.w * k4.w;
    }
    #pragma unroll 8
    for (int kk = 0; kk < 128; kk += 4) {
        const float4 g4 = ld_bf16x4(gp + kk);
        const float4 a4 = *(const float4*)(&attrf[j][kk]);
        dot += a4.x * g4.x + a4.y * g4.y + a4.z * g4.z + a4.w * g4.w;
    }
    p1[(size_t)e * 8 + h] = __expf(fminf(dot * RSQRT32, 80.f));
}

// ---------------- aggregate layer 1 (dst-centric) ----------------
__global__ __launch_bounds__(256) void k_aggB1(
    const int* __restrict__ startA, const int* __restrict__ srcS,
    const int* __restrict__ orig, const float* __restrict__ relT,
    const float* __restrict__ msg, const float* __restrict__ tw,
    const float* __restrict__ tb,
    const float* __restrict__ p1, const unsigned short* __restrict__ V1b,
    unsigned short* __restrict__ A1b, float* __restrict__ numv1,
    float* __restrict__ s1)
{
    const int t = threadIdx.x;
    const int g = t >> 5, l = t & 31;
    const int d = blockIdx.x * 8 + g;
    const int eb = startA[d], ee = startA[d + 1];
    const int hl = l >> 2, cl0 = (l & 3) * 8;

    float4 twl = make_float4(0.f,0.f,0.f,0.f), tbl = twl;
    if (l < 16) {
        twl = *(const float4*)(tw + l * 4);
        tbl = *(const float4*)(tb + l * 4);
    }
    float a1acc[8][4] = {};
    float nv[8] = {};
    float sacc = 0.f;

    for (int e = eb; e < ee; ++e) {
        const int s = srcS[e];
        const float4 p03 = *(const float4*)(p1 + (size_t)e * 8);
        const float4 p47 = *(const float4*)(p1 + (size_t)e * 8 + 4);
        float a[4];
        if (l < 16) {
            const float rt = relT[e];
            a[0] = __cosf(rt * twl.x + tbl.x);
            a[1] = __cosf(rt * twl.y + tbl.y);
            a[2] = __cosf(rt * twl.z + tbl.z);
            a[3] = __cosf(rt * twl.w + tbl.w);
        } else {
            const int oe = orig[e];
            const float4 m4 = *(const float4*)(msg + (size_t)oe * 64 + (l - 16) * 4);
            a[0] = m4.x; a[1] = m4.y; a[2] = m4.z; a[3] = m4.w;
        }
        #pragma unroll
        for (int i = 0; i < 4; ++i) {
            a1acc[0][i] += p03.x * a[i];
            a1acc[1][i] += p03.y * a[i];
            a1acc[2][i] += p03.z * a[i];
            a1acc[3][i] += p03.w * a[i];
            a1acc[4][i] += p47.x * a[i];
            a1acc[5][i] += p47.y * a[i];
            a1acc[6][i] += p47.z * a[i];
            a1acc[7][i] += p47.w * a[i];
        }
        const float pv = p1[(size_t)e * 8 + hl];
        const unsigned short* vp = V1b + (size_t)s * 256 + hl * 32 + cl0;
        const float4 v0 = ld_bf16x4(vp);
        const float4 v1 = ld_bf16x4(vp + 4);
        nv[0] += pv * v0.x; nv[1] += pv * v0.y; nv[2] += pv * v0.z; nv[3] += pv * v0.w;
        nv[4] += pv * v1.x; nv[5] += pv * v1.y; nv[6] += pv * v1.z; nv[7] += pv * v1.w;
        if (l < 8) sacc += p1[(size_t)e * 8 + l];
    }
    #pragma unroll
    for (int h = 0; h < 8; ++h)
        *(ushort4*)(A1b + (size_t)d * 1024 + h * 128 + l * 4) =
            st_bf16x4(a1acc[h][0], a1acc[h][1], a1acc[h][2], a1acc[h][3]);
    float* np = numv1 + (size_t)d * 256 + hl * 32 + cl0;
    *(float4*)(np)     = make_float4(nv[0], nv[1], nv[2], nv[3]);
    *(float4*)(np + 4) = make_float4(nv[4], nv[5], nv[6], nv[7]);
    if (l < 8) s1[(size_t)d * 8 + l] = sacc;
}

// ---------------- MFMA fold layer 1: h = relu((numv1 + A1@We1)/s1 + skip) ------
__global__ __launch_bounds__(256) void k_foldC1m(
    const unsigned short* __restrict__ A1b, const unsigned short* __restrict__ WF1,
    const float* __restrict__ numv1, const float* __restrict__ s1,
    const unsigned short* __restrict__ S1mb, unsigned short* __restrict__ hb)
{
    __shared__ unsigned short As[64 * 136];
    __shared__ unsigned short Bs[32 * 136];
    const int t = threadIdx.x;
    const int n0 = blockIdx.x * 64;
    const int h = blockIdx.y;
    { // stage A: A1b slice [64][128]
        const int n = t >> 2, kk = (t & 3) * 32;
        const int gn = n0 + n;
        unsigned short* dst = As + n * 136 + kk;
        if (gn < NN) {
            const unsigned short* src = A1b + (size_t)gn * 1024 + h * 128 + kk;
            #pragma unroll
            for (int i = 0; i < 4; ++i)
                *(bf16x8*)(dst + 8 * i) = *(const bf16x8*)(src + 8 * i);
        } else {
            const bf16x8 z = {};
            #pragma unroll
            for (int i = 0; i < 4; ++i) *(bf16x8*)(dst + 8 * i) = z;
        }
    }
    { // stage B^T: WF1[h] [32][128]
        const int c = t >> 3, kk = (t & 7) * 16;
        const unsigned short* src = WF1 + (size_t)h * 4096 + c * 128 + kk;
        *(bf16x8*)(Bs + c * 136 + kk) = *(const bf16x8*)(src);
        *(bf16x8*)(Bs + c * 136 + kk + 8) = *(const bf16x8*)(src + 8);
    }
    __syncthreads();

    const int w = t >> 6, lane = t & 63, m = lane & 15, quad = lane >> 4;
    f32x4 acc[2];
    acc[0] = (f32x4){0.f, 0.f, 0.f, 0.f};
    acc[1] = (f32x4){0.f, 0.f, 0.f, 0.f};
    #pragma unroll
    for (int kc = 0; kc < 4; ++kc) {
        const bf16x8 af = *(const bf16x8*)(As + (16 * w + m) * 136 + kc * 32 + quad * 8);
        #pragma unroll
        for (int ct = 0; ct < 2; ++ct) {
            const bf16x8 bf = *(const bf16x8*)(Bs + (16 * ct + m) * 136 + kc * 32 + quad * 8);
            acc[ct] = MFMA_B16(af, bf, acc[ct]);
        }
    }
    #pragma unroll
    for (int ct = 0; ct < 2; ++ct) {
        const int c = ct * 16 + m;
        #pragma unroll
        for (int r = 0; r < 4; ++r) {
            const int gn = n0 + 16 * w + quad * 4 + r;
            if (gn < NN) {
                const float s = s1[(size_t)gn * 8 + h] + 1e-16f;
                const float nv = numv1[(size_t)gn * 256 + h * 32 + c];
                const float sk = bf2f(S1mb[(size_t)gn * 256 + h * 32 + c]);
                float v = (acc[ct][r] + nv) / s + sk;
                v = v > 0.f ? v : 0.f;
                hb[(size_t)gn * 256 + h * 32 + c] = f2bf(v);
            }
        }
    }
}

// ---------------- MFMA node GEMM layer 2: h(bf16) @ 4x(256x32), fp32 out -------
__global__ __launch_bounds__(256) void k_gemm2m(
    const unsigned short* __restrict__ hb, const unsigned short* __restrict__ WB2,
    const float* __restrict__ c0, const float* __restrict__ c1,
    const float* __restrict__ c2, const float* __restrict__ c3,
    float* __restrict__ O0, float* __restrict__ O1,
    float* __restrict__ O2, float* __restrict__ O3)
{
    __shared__ unsigned short As[64 * 136];
    __shared__ unsigned short Bs[64 * 136];
    const int t = threadIdx.x;
    const int row0 = blockIdx.x * 64;
    const int coly = blockIdx.y;              // 0..1, 64 cols each
    const int w = t >> 6, lane = t & 63, m = lane & 15, quad = lane >> 4;

    f32x4 acc[4];
    #pragma unroll
    for (int i = 0; i < 4; ++i) acc[i] = (f32x4){0.f, 0.f, 0.f, 0.f};

    for (int kb = 0; kb < 2; ++kb) {
        if (kb) __syncthreads();
        { // stage A chunk [64][128]
            const int r = t >> 2, kk = (t & 3) * 32;
            const int gr = row0 + r;
            unsigned short* dst = As + r * 136 + kk;
            if (gr < NN) {
                const unsigned short* src = hb + (size_t)gr * 256 + kb * 128 + kk;
                #pragma unroll
                for (int i = 0; i < 4; ++i)
                    *(bf16x8*)(dst + 8 * i) = *(const bf16x8*)(src + 8 * i);
            } else {
                const bf16x8 z = {};
                #pragma unroll
                for (int i = 0; i < 4; ++i) *(bf16x8*)(dst + 8 * i) = z;
            }
        }
        { // stage B^T chunk [64][128]
            const int n = t >> 2, kk = (t & 3) * 32;
            const unsigned short* src = WB2 + (size_t)(coly * 64 + n) * 256 + kb * 128 + kk;
            unsigned short* dst = Bs + n * 136 + kk;
            #pragma unroll
            for (int i = 0; i < 4; ++i)
                *(bf16x8*)(dst + 8 * i) = *(const bf16x8*)(src + 8 * i);
        }
        __syncthreads();
        #pragma unroll
        for (int kc = 0; kc < 4; ++kc) {
            const bf16x8 af = *(const bf16x8*)(As + (16 * w + m) * 136 + kc * 32 + quad * 8);
            #pragma unroll
            for (int ct = 0; ct < 4; ++ct) {
                const bf16x8 bf = *(const bf16x8*)(Bs + (16 * ct + m) * 136 + kc * 32 + quad * 8);
                acc[ct] = MFMA_B16(af, bf, acc[ct]);
            }
        }
    }
    #pragma unroll
    for (int ct = 0; ct < 4; ++ct) {
        const int col = coly * 64 + ct * 16 + m;
        const int part = col >> 5, pc = col & 31;
        const float* bb = part == 0 ? c0 : part == 1 ? c1 : part == 2 ? c2 : c3;
        float* Op = part == 0 ? O0 : part == 1 ? O1 : part == 2 ? O2 : O3;
        const float b = bb[pc];
        #pragma unroll
        for (int r = 0; r < 4; ++r) {
            const int gr = row0 + 16 * w + quad * 4 + r;
            if (gr < NN) Op[(size_t)gr * 32 + pc] = acc[ct][r] + b;
        }
    }
}

// ---------------- layer 2 fused p + aggregate ----------------
__global__ __launch_bounds__(256) void k_aggB2(
    const int* __restrict__ startA, const int* __restrict__ srcS,
    const int* __restrict__ orig, const float* __restrict__ relT,
    const float* __restrict__ msg, const float* __restrict__ tw,
    const float* __restrict__ tb,
    const float* __restrict__ Q2, const float* __restrict__ K2,
    const float* __restrict__ V2, const float* __restrict__ G2,
    float* __restrict__ A2, float* __restrict__ numv2, float* __restrict__ s2)
{
    const int t = threadIdx.x;
    const int g = t >> 5, l = t & 31;
    const int d = blockIdx.x * 8 + g;
    const int eb = startA[d], ee = startA[d + 1];

    const float q2l = Q2[(size_t)d * 32 + l];
    const float4 g2l = *(const float4*)(G2 + (size_t)d * 128 + l * 4);
    float4 twl = make_float4(0.f,0.f,0.f,0.f), tbl = twl;
    if (l < 16) {
        twl = *(const float4*)(tw + l * 4);
        tbl = *(const float4*)(tb + l * 4);
    }
    float acc2[4] = {};
    float nvacc = 0.f, sacc = 0.f;

    for (int e = eb; e < ee; ++e) {
        const int s = srcS[e];
        float a[4];
        if (l < 16) {
            const float rt = relT[e];
            a[0] = __cosf(rt * twl.x + tbl.x);
            a[1] = __cosf(rt * twl.y + tbl.y);
            a[2] = __cosf(rt * twl.z + tbl.z);
            a[3] = __cosf(rt * twl.w + tbl.w);
        } else {
            const int oe = orig[e];
            const float4 m4 = *(const float4*)(msg + (size_t)oe * 64 + (l - 16) * 4);
            a[0] = m4.x; a[1] = m4.y; a[2] = m4.z; a[3] = m4.w;
        }
        float part = q2l * K2[(size_t)s * 32 + l];
        part += a[0] * g2l.x + a[1] * g2l.y + a[2] * g2l.z + a[3] * g2l.w;
        part += __shfl_xor(part, 1);
        part += __shfl_xor(part, 2);
        part += __shfl_xor(part, 4);
        part += __shfl_xor(part, 8);
        part += __shfl_xor(part, 16);
        const float p = __expf(fminf(part * RSQRT32, 80.f));
        acc2[0] += p * a[0]; acc2[1] += p * a[1];
        acc2[2] += p * a[2]; acc2[3] += p * a[3];
        nvacc += p * V2[(size_t)s * 32 + l];
        sacc += p;
    }
    *(float4*)(A2 + (size_t)d * 128 + l * 4) =
        make_float4(acc2[0], acc2[1], acc2[2], acc2[3]);
    numv2[(size_t)d * 32 + l] = nvacc;
    if (l == 0) s2[d] = sacc;
}

// ---------------- fold layer 2 ----------------
__global__ __launch_bounds__(256) void k_foldC2(
    const float* __restrict__ A2, const float* __restrict__ We2,
    const float* __restrict__ numv2, const float* __restrict__ s2,
    const float* __restrict__ S2m, float* __restrict__ out)
{
    __shared__ float Ws[128][36];
    const int t = threadIdx.x;
    {
        const int k = t >> 1, c16 = (t & 1) * 16;
        #pragma unroll
        for (int i = 0; i < 4; ++i)
            *(float4*)(&Ws[k][c16 + 4 * i]) =
                *(const float4*)(We2 + (size_t)k * 32 + c16 + 4 * i);
    }
    __syncthreads();
    const int n = blockIdx.x * 8 + (t >> 5);
    const int c = t & 31;
    const float* ap = A2 + (size_t)n * 128;
    float acc = 0.f;
    #pragma unroll 8
    for (int k = 0; k < 128; k += 4) {
        const float4 a4 = *(const float4*)(ap + k);
        acc += a4.x * Ws[k][c] + a4.y * Ws[k + 1][c] +
               a4.z * Ws[k + 2][c] + a4.w * Ws[k + 3][c];
    }
    const float s = s2[n] + 1e-16f;
    float v = (numv2[(size_t)n * 32 + c] + acc) / s + S2m[(size_t)n * 32 + c];
    out[(size_t)n * 32 + c] = v > 0.f ? v : 0.f;
}

extern "C" void kernel_launch(void* const* d_in, const int* in_sizes, int n_in,
                              void* d_out, int out_size, void* d_ws, size_t ws_size,
                              hipStream_t stream) {
    const float* x   = (const float*)d_in[0];
    const float* lu  = (const float*)d_in[1];
    const void*  ei  = d_in[2];
    const float* tE  = (const float*)d_in[3];
    const float* msg = (const float*)d_in[4];
    const float* tw  = (const float*)d_in[5];
    const float* tb  = (const float*)d_in[6];
    const float* Wq1 = (const float*)d_in[7];  const float* bq1 = (const float*)d_in[8];
    const float* Wk1 = (const float*)d_in[9];  const float* bk1 = (const float*)d_in[10];
    const float* Wv1 = (const float*)d_in[11]; const float* bv1 = (const float*)d_in[12];
    const float* We1 = (const float*)d_in[13];
    const float* Ws1 = (const float*)d_in[14]; const float* bs1 = (const float*)d_in[15];
    const float* Wq2 = (const float*)d_in[16]; const float* bq2 = (const float*)d_in[17];
    const float* Wk2 = (const float*)d_in[18]; const float* bk2 = (const float*)d_in[19];
    const float* Wv2 = (const float*)d_in[20]; const float* bv2 = (const float*)d_in[21];
    const float* We2 = (const float*)d_in[22];
    const float* Ws2 = (const float*)d_in[23]; const float* bs2 = (const float*)d_in[24];
    float* out = (float*)d_out;
    char* ws = (char*)d_ws;

    if (ws_size < WS_TOTAL) return;

    int* flag   = (int*)(ws + O_FLAG);
    int* srcI   = (int*)(ws + O_SRCI);
    int* dstI   = (int*)(ws + O_DSTI);
    int* deg    = (int*)(ws + O_DEG);
    int* cursor = (int*)(ws + O_CUR);
    int* startA = (int*)(ws + O_START);
    int* srcS   = (int*)(ws + O_SRCS);
    int* dstS   = (int*)(ws + O_DSTS);
    int* orig   = (int*)(ws + O_ORIG);
    float* relT = (float*)(ws + O_RELT);
    unsigned short* Q1b  = (unsigned short*)(ws + O_Q1);
    unsigned short* K1b  = (unsigned short*)(ws + O_K1);
    unsigned short* V1b  = (unsigned short*)(ws + O_V1);
    unsigned short* S1mb = (unsigned short*)(ws + O_S1M);
    unsigned short* G1b  = (unsigned short*)(ws + O_G1);
    float* p1   = (float*)(ws + O_P1);
    unsigned short* A1b  = (unsigned short*)(ws + O_A1);
    float* numv1 = (float*)(ws + O_NUMV1);
    float* s1    = (float*)(ws + O_S1);
    unsigned short* hb = (unsigned short*)(ws + O_H);
    float* Q2   = (float*)(ws + O_Q2);
    float* K2m  = (float*)(ws + O_K2);
    float* V2m  = (float*)(ws + O_V2);
    float* S2m  = (float*)(ws + O_S2M);
    float* G2   = (float*)(ws + O_G2);
    float* A2   = (float*)(ws + O_A2);
    float* numv2 = (float*)(ws + O_NUMV2);
    float* s2   = (float*)(ws + O_S2);
    unsigned short* WB1 = (unsigned short*)(ws + O_WB1);
    unsigned short* WG1 = (unsigned short*)(ws + O_WG1);
    unsigned short* WF1 = (unsigned short*)(ws + O_WF1);
    unsigned short* WB2 = (unsigned short*)(ws + O_WB2);

    hipMemsetAsync(ws + O_DEG, 0, 200000, stream);

    k_detect<<<1, 64, 0, stream>>>((const unsigned int*)ei, flag);
    k_convert<<<(NE + 255) / 256, 256, 0, stream>>>(ei, flag, srcI, dstI);
    k_hist<<<(NE + 255) / 256, 256, 0, stream>>>(dstI, deg);
    k_scan<<<1, 256, 0, stream>>>(deg, startA, cursor);
    k_scatter<<<(NE + 255) / 256, 256, 0, stream>>>(srcI, dstI, lu, tE, cursor,
                                                    srcS, dstS, orig, relT);
    k_prepw<<<896, 256, 0, stream>>>(Wq1, Wk1, Wv1, Ws1, We1, Wq2, Wk2, Wv2, Ws2,
                                     WB1, WG1, WF1, WB2);
    k_gemm1m<<<dim3(782, 16), 256, 0, stream>>>(
        x, WB1, bq1, bk1, bv1, bs1, Q1b, K1b, V1b, S1mb);
    k_g1m<<<dim3(782, 8), 256, 0, stream>>>(Q1b, WG1, G1b);
    k_pA1<<<NE / 32, 256, 0, stream>>>(srcS, dstS, orig, relT, msg, tw, tb,
                                       Q1b, K1b, G1b, p1);
    k_aggB1<<<NN / 8, 256, 0, stream>>>(startA, srcS, orig, relT, msg, tw, tb,
                                        p1, V1b, A1b, numv1, s1);
    k_foldC1m<<<dim3(782, 8), 256, 0, stream>>>(A1b, WF1, numv1, s1, S1mb, hb);
    k_gemm2m<<<dim3(782, 2), 256, 0, stream>>>(
        hb, WB2, bq2, bk2, bv2, bs2, Q2, K2m, V2m, S2m);
    k_g2<<<782, 256, 0, stream>>>(Q2, We2, G2);
    k_aggB2<<<NN / 8, 256, 0, stream>>>(startA, srcS, orig, relT, msg, tw, tb,
                                        Q2, K2m, V2m, G2, A2, numv2, s2);
    k_foldC2<<<NN / 8, 256, 0, stream>>>(A2, We2, numv2, s2, S2m, out);
}

// Round 5
// 856.945 us; speedup vs baseline: 7.3353x; 1.1701x over previous
//
#include <hip/hip_runtime.h>
#include <math.h>

#define NN 50000
#define NE 400000
#define RSQRT32 0.17677669529663687f

typedef __attribute__((ext_vector_type(8))) short bf16x8;
typedef __attribute__((ext_vector_type(4))) float f32x4;
#define MFMA_B16(a, b, c) __builtin_amdgcn_mfma_f32_16x16x32_bf16(a, b, c, 0, 0, 0)

// ---------------- workspace layout (bytes) ----------------
#define O_FLAG  0ULL
#define O_BSUM  256ULL                         // 196 ints (scan block sums)
#define O_SRCI  1280ULL                        // E*4
#define O_DSTI  (O_SRCI + 1600000ULL)          // E*4 -> s1 alias after scatter
#define O_DEG   (O_DSTI + 1600000ULL)          // N*4
#define O_CUR   (O_DEG + 200192ULL)            // N*4 -> s2 alias
#define O_START (O_CUR + 200192ULL)            // (N+1)*4
#define O_SRCS  (O_START + 200704ULL)          // E*4
#define O_ORIG  (O_SRCS + 1600000ULL)          // E*4
#define O_RELT  (O_ORIG + 1600000ULL)          // E*4
#define O_Q1    (O_RELT + 1600000ULL)          // N*256*2 bf16; later Q2/K2/V2/S2m fp32
#define O_K1    (O_Q1 + 25600000ULL)           // bf16; later G2 fp32
#define O_V1    (O_K1 + 25600000ULL)           // bf16; later h bf16
#define O_S1M   (O_V1 + 25600000ULL)           // bf16; later A2 fp32
#define O_G1    (O_S1M + 25600000ULL)          // N*1024*2 bf16; A1 aliases exactly; later numv2
#define O_WB1   (O_G1 + 102400000ULL)          // [4][256][128] bf16
#define O_WG1   (O_WB1 + 262144ULL)            // [8][128][32] bf16
#define O_WF1   (O_WG1 + 65536ULL)             // [8][32][128] bf16
#define O_WB2   (O_WF1 + 65536ULL)             // [128][256] bf16
#define O_NUMV1 (O_WB2 + 65536ULL)             // N*256*4 fp32 (dedicated: Q1/K1 live during agg)
#define WS_TOTAL (O_NUMV1 + 51200000ULL)
// aliases
#define O_S1    O_DSTI                         // N*8*4
#define O_A1    O_G1                           // N*1024*2 bf16 (exact overlay of G1)
#define O_H     O_V1                           // N*256*2 bf16
#define O_Q2    O_Q1                           // N*32*4 fp32
#define O_K2    (O_Q1 + 6400000ULL)
#define O_V2    (O_Q1 + 12800000ULL)
#define O_S2M   (O_Q1 + 19200000ULL)
#define O_G2    O_K1                           // N*128*4 fp32
#define O_A2    O_S1M                          // N*128*4 fp32
#define O_NUMV2 O_G1                           // N*32*4 fp32
#define O_S2    O_CUR                          // N*4

__device__ __forceinline__ unsigned short f2bf(float f) {
    unsigned int u = __float_as_uint(f);
    unsigned int r = (u + 0x7fffu + ((u >> 16) & 1u)) >> 16;
    return (unsigned short)r;
}
__device__ __forceinline__ float bf2f(unsigned short u) {
    return __uint_as_float(((unsigned int)u) << 16);
}
__device__ __forceinline__ float4 ld_bf16x4(const unsigned short* p) {
    const ushort4 u = *(const ushort4*)p;
    float4 r;
    r.x = bf2f(u.x); r.y = bf2f(u.y); r.z = bf2f(u.z); r.w = bf2f(u.w);
    return r;
}
__device__ __forceinline__ ushort4 st_bf16x4(float a, float b, float c, float d) {
    ushort4 u; u.x = f2bf(a); u.y = f2bf(b); u.z = f2bf(c); u.w = f2bf(d);
    return u;
}

// ---------------- index dtype detect ----------------
__global__ void k_detect(const unsigned int* ei, int* flag) {
    if (threadIdx.x == 0) {
        int is64 = 1;
        for (int i = 0; i < 64; ++i)
            if (ei[2 * i + 1] != 0u) { is64 = 0; break; }
        *flag = is64;
    }
}

// ---------------- convert + degree histogram (fused) ----------------
__global__ void k_convhist(const void* ei, const int* flag,
                           int* __restrict__ srcI, int* __restrict__ dstI,
                           int* __restrict__ deg) {
    int i = blockIdx.x * 256 + threadIdx.x;
    if (i >= NE) return;
    int s, d;
    if (*flag) {
        const long long* p = (const long long*)ei;
        s = (int)p[i]; d = (int)p[NE + i];
    } else {
        const int* p = (const int*)ei;
        s = p[i]; d = p[NE + i];
    }
    srcI[i] = s;
    dstI[i] = d;
    atomicAdd(&deg[d], 1);
}

// ---------------- parallel 3-phase exclusive scan over deg ----------------
__global__ void k_scanA(const int* __restrict__ deg, int* __restrict__ locs,
                        int* __restrict__ bsum) {
    __shared__ int sm[256];
    const int t = threadIdx.x;
    const int gidx = blockIdx.x * 256 + t;
    int v = (gidx < NN) ? deg[gidx] : 0;
    sm[t] = v;
    __syncthreads();
    for (int off = 1; off < 256; off <<= 1) {
        int u = (t >= off) ? sm[t - off] : 0;
        __syncthreads();
        sm[t] += u;
        __syncthreads();
    }
    if (gidx < NN) locs[gidx] = sm[t];          // inclusive local scan
    if (t == 255) bsum[blockIdx.x] = sm[255];
}

__global__ void k_scanB(int* __restrict__ bsum) {
    __shared__ int sm[256];
    const int t = threadIdx.x;
    int v = (t < 196) ? bsum[t] : 0;
    sm[t] = v;
    __syncthreads();
    for (int off = 1; off < 256; off <<= 1) {
        int u = (t >= off) ? sm[t - off] : 0;
        __syncthreads();
        sm[t] += u;
        __syncthreads();
    }
    if (t < 196) bsum[t] = sm[t] - v;           // exclusive block offsets
}

__global__ void k_scanC(const int* __restrict__ deg, const int* __restrict__ bsum,
                        int* __restrict__ startA, int* __restrict__ cursor) {
    const int t = threadIdx.x;
    const int gidx = blockIdx.x * 256 + t;
    if (gidx < NN) {
        const int ex = startA[gidx] - deg[gidx] + bsum[blockIdx.x];
        startA[gidx] = ex;
        cursor[gidx] = ex;
    }
    if (gidx == 0) startA[NN] = NE;
}

__global__ void k_scatter(const int* __restrict__ srcI, const int* __restrict__ dstI,
                          const float* __restrict__ lu, const float* __restrict__ tE,
                          int* __restrict__ cursor,
                          int* __restrict__ srcS, int* __restrict__ orig,
                          float* __restrict__ relT) {
    int i = blockIdx.x * 256 + threadIdx.x;
    if (i >= NE) return;
    const int d = dstI[i];
    const int s = srcI[i];
    const int pos = atomicAdd(&cursor[d], 1);
    srcS[pos] = s;
    orig[pos] = i;
    relT[pos] = lu[s] - tE[i];
}

// ---------------- weight prep: pack bf16 B^T forms ----------------
__global__ void k_prepw(
    const float* __restrict__ Wq1, const float* __restrict__ Wk1,
    const float* __restrict__ Wv1, const float* __restrict__ Ws1,
    const float* __restrict__ We1,
    const float* __restrict__ Wq2, const float* __restrict__ Wk2,
    const float* __restrict__ Wv2, const float* __restrict__ Ws2,
    unsigned short* __restrict__ WB1, unsigned short* __restrict__ WG1,
    unsigned short* __restrict__ WF1, unsigned short* __restrict__ WB2)
{
    const int i = blockIdx.x * 256 + threadIdx.x;
    if (i < 131072) {                       // WB1[part][n 256][k 128]
        const int part = i >> 15;
        const int rem = i & 32767;
        const int n = rem >> 7, k = rem & 127;
        const float* W = part == 0 ? Wq1 : part == 1 ? Wk1 : part == 2 ? Wv1 : Ws1;
        WB1[i] = f2bf(W[(size_t)k * 256 + n]);
    } else if (i < 163840) {                // WG1[h][ko 128][c 32]
        const int j = i - 131072;
        const int h = j >> 12, ko = (j >> 5) & 127, c = j & 31;
        WG1[j] = f2bf(We1[(size_t)ko * 256 + h * 32 + c]);
    } else if (i < 196608) {                // WF1[h][c 32][ko 128]
        const int j = i - 163840;
        const int h = j >> 12, c = (j >> 7) & 31, ko = j & 127;
        WF1[j] = f2bf(We1[(size_t)ko * 256 + h * 32 + c]);
    } else if (i < 229376) {                // WB2[col 128][k 256]
        const int j = i - 196608;
        const int col = j >> 8, k = j & 255;
        const int part = col >> 5, pc = col & 31;
        const float* W = part == 0 ? Wq2 : part == 1 ? Wk2 : part == 2 ? Wv2 : Ws2;
        WB2[j] = f2bf(W[(size_t)k * 32 + pc]);
    }
}

// ---------------- MFMA node GEMM layer 1 ----------------
__global__ __launch_bounds__(256) void k_gemm1m(
    const float* __restrict__ x, const unsigned short* __restrict__ WB1,
    const float* __restrict__ c0, const float* __restrict__ c1,
    const float* __restrict__ c2, const float* __restrict__ c3,
    unsigned short* __restrict__ Q1b, unsigned short* __restrict__ K1b,
    unsigned short* __restrict__ V1b, unsigned short* __restrict__ S1mb)
{
    __shared__ unsigned short As[64 * 136];
    __shared__ unsigned short Bs[64 * 136];
    const int t = threadIdx.x;
    const int row0 = blockIdx.x * 64;
    const int by = blockIdx.y;
    const int part = by >> 2;
    const int pcol0 = (by & 3) * 64;
    const float* bp = part == 0 ? c0 : part == 1 ? c1 : part == 2 ? c2 : c3;
    unsigned short* Ob = part == 0 ? Q1b : part == 1 ? K1b : part == 2 ? V1b : S1mb;

    {
        const int r = t >> 2, cc = (t & 3) * 32;
        const int gr = row0 + r;
        unsigned short* dst = As + r * 136 + cc;
        if (gr < NN) {
            const float4* xp = (const float4*)(x + (size_t)gr * 128 + cc);
            #pragma unroll
            for (int i = 0; i < 8; ++i) {
                const float4 v = xp[i];
                *(ushort4*)(dst + 4 * i) = st_bf16x4(v.x, v.y, v.z, v.w);
            }
        } else {
            const ushort4 z = {0, 0, 0, 0};
            #pragma unroll
            for (int i = 0; i < 8; ++i) *(ushort4*)(dst + 4 * i) = z;
        }
    }
    {
        const int n = t >> 2, kk = (t & 3) * 32;
        const unsigned short* src = WB1 + ((size_t)part * 256 + pcol0 + n) * 128 + kk;
        unsigned short* dst = Bs + n * 136 + kk;
        #pragma unroll
        for (int i = 0; i < 4; ++i)
            *(bf16x8*)(dst + 8 * i) = *(const bf16x8*)(src + 8 * i);
    }
    __syncthreads();

    const int w = t >> 6, lane = t & 63, m = lane & 15, quad = lane >> 4;
    f32x4 acc[4];
    #pragma unroll
    for (int i = 0; i < 4; ++i) acc[i] = (f32x4){0.f, 0.f, 0.f, 0.f};
    #pragma unroll
    for (int kc = 0; kc < 4; ++kc) {
        const bf16x8 af = *(const bf16x8*)(As + (16 * w + m) * 136 + kc * 32 + quad * 8);
        #pragma unroll
        for (int ct = 0; ct < 4; ++ct) {
            const bf16x8 bf = *(const bf16x8*)(Bs + (16 * ct + m) * 136 + kc * 32 + quad * 8);
            acc[ct] = MFMA_B16(af, bf, acc[ct]);
        }
    }
    #pragma unroll
    for (int ct = 0; ct < 4; ++ct) {
        const int colp = pcol0 + ct * 16 + m;
        const float b = bp[colp];
        #pragma unroll
        for (int r = 0; r < 4; ++r) {
            const int gr = row0 + 16 * w + quad * 4 + r;
            if (gr < NN) Ob[(size_t)gr * 256 + colp] = f2bf(acc[ct][r] + b);
        }
    }
}

// ---------------- MFMA G1 ----------------
__global__ __launch_bounds__(256) void k_g1m(
    const unsigned short* __restrict__ Q1b, const unsigned short* __restrict__ WG1,
    unsigned short* __restrict__ G1b)
{
    __shared__ unsigned short As[64 * 40];
    __shared__ unsigned short Bs[128 * 40];
    const int t = threadIdx.x;
    const int n0 = blockIdx.x * 64;
    const int h = blockIdx.y;
    {
        const int n = t >> 2, c = (t & 3) * 8;
        const int gn = n0 + n;
        bf16x8 v = {};
        if (gn < NN) v = *(const bf16x8*)(Q1b + (size_t)gn * 256 + h * 32 + c);
        *(bf16x8*)(As + n * 40 + c) = v;
    }
    {
        const int ko = t >> 1, c = (t & 1) * 16;
        const unsigned short* src = WG1 + (size_t)h * 4096 + ko * 32 + c;
        *(bf16x8*)(Bs + ko * 40 + c) = *(const bf16x8*)(src);
        *(bf16x8*)(Bs + ko * 40 + c + 8) = *(const bf16x8*)(src + 8);
    }
    __syncthreads();

    const int w = t >> 6, lane = t & 63, m = lane & 15, quad = lane >> 4;
    f32x4 acc[8];
    #pragma unroll
    for (int i = 0; i < 8; ++i) acc[i] = (f32x4){0.f, 0.f, 0.f, 0.f};
    const bf16x8 af = *(const bf16x8*)(As + (16 * w + m) * 40 + quad * 8);
    #pragma unroll
    for (int ct = 0; ct < 8; ++ct) {
        const bf16x8 bf = *(const bf16x8*)(Bs + (16 * ct + m) * 40 + quad * 8);
        acc[ct] = MFMA_B16(af, bf, acc[ct]);
    }
    #pragma unroll
    for (int ct = 0; ct < 8; ++ct) {
        const int k = ct * 16 + m;
        #pragma unroll
        for (int r = 0; r < 4; ++r) {
            const int gn = n0 + 16 * w + quad * 4 + r;
            if (gn < NN) G1b[(size_t)gn * 1024 + h * 128 + k] = f2bf(acc[ct][r]);
        }
    }
}

// ---------------- G2 (fp32) ----------------
__global__ __launch_bounds__(256) void k_g2(
    const float* __restrict__ Q2, const float* __restrict__ We2,
    float* __restrict__ G2)
{
    __shared__ float Qs[64][36];
    __shared__ float Ws[128][36];
    const int t = threadIdx.x;
    const int n0 = blockIdx.x * 64;
    {
        const int n = t >> 2, c8 = (t & 3) * 8;
        float4 v0 = make_float4(0.f,0.f,0.f,0.f), v1 = v0;
        if (n0 + n < NN) {
            v0 = *(const float4*)(Q2 + (size_t)(n0 + n) * 32 + c8);
            v1 = *(const float4*)(Q2 + (size_t)(n0 + n) * 32 + c8 + 4);
        }
        *(float4*)(&Qs[n][c8]) = v0;
        *(float4*)(&Qs[n][c8 + 4]) = v1;
    }
    {
        const int k = t >> 1, c16 = (t & 1) * 16;
        #pragma unroll
        for (int i = 0; i < 4; ++i)
            *(float4*)(&Ws[k][c16 + 4 * i]) =
                *(const float4*)(We2 + (size_t)k * 32 + c16 + 4 * i);
    }
    __syncthreads();
    const int tx = t & 15, ty = t >> 4;
    const int k8 = tx * 8, n4 = ty * 4;
    float acc[4][8] = {};
    #pragma unroll 8
    for (int c = 0; c < 32; ++c) {
        float a[4], b[8];
        #pragma unroll
        for (int i = 0; i < 4; ++i) a[i] = Qs[n4 + i][c];
        #pragma unroll
        for (int j = 0; j < 8; ++j) b[j] = Ws[k8 + j][c];
        #pragma unroll
        for (int i = 0; i < 4; ++i)
            #pragma unroll
            for (int j = 0; j < 8; ++j)
                acc[i][j] += a[i] * b[j];
    }
    #pragma unroll
    for (int i = 0; i < 4; ++i) {
        const int gn = n0 + n4 + i;
        if (gn < NN) {
            float* gp = G2 + (size_t)gn * 128 + k8;
            *(float4*)(gp)     = make_float4(acc[i][0], acc[i][1], acc[i][2], acc[i][3]);
            *(float4*)(gp + 4) = make_float4(acc[i][4], acc[i][5], acc[i][6], acc[i][7]);
        }
    }
}

// ---------------- FUSED layer-1 attention + aggregation (dst-centric) ----------
// block = 8 dsts x 32 lanes. Per edge: logits via per-head partials + 32-lane
// butterfly, exp, then in-register A1/numv/s accumulation. No LDS, no atomics.
// A1b may alias G1b exactly (g loaded into regs before any store; all stored
// values data-depend on the loads).
__global__ __launch_bounds__(256, 4) void k_agg1(
    const int* __restrict__ startA, const int* __restrict__ srcS,
    const int* __restrict__ orig, const float* __restrict__ relT,
    const float* __restrict__ msg, const float* __restrict__ tw,
    const float* __restrict__ tb,
    const unsigned short* __restrict__ Q1b, const unsigned short* __restrict__ K1b,
    const unsigned short* __restrict__ V1b, const unsigned short* G1b,
    unsigned short* A1b, float* __restrict__ numv1, float* __restrict__ s1)
{
    const int t = threadIdx.x;
    const int g = t >> 5, l = t & 31;
    const int lane64 = t & 63;
    const int d = blockIdx.x * 8 + g;
    const int eb = startA[d], ee = startA[d + 1];
    const int hl = l >> 2;   // head owning this lane's 8-channel q/k/v slice

    float q8[8];
    {
        const unsigned short* qp = Q1b + (size_t)d * 256 + l * 8;
        const float4 q0 = ld_bf16x4(qp), q1 = ld_bf16x4(qp + 4);
        q8[0]=q0.x; q8[1]=q0.y; q8[2]=q0.z; q8[3]=q0.w;
        q8[4]=q1.x; q8[5]=q1.y; q8[6]=q1.z; q8[7]=q1.w;
    }
    float gv[8][4];
    #pragma unroll
    for (int h = 0; h < 8; ++h) {
        const float4 gg = ld_bf16x4(G1b + (size_t)d * 1024 + h * 128 + l * 4);
        gv[h][0]=gg.x; gv[h][1]=gg.y; gv[h][2]=gg.z; gv[h][3]=gg.w;
    }
    float4 twl = make_float4(0.f,0.f,0.f,0.f), tbl = twl;
    if (l < 16) {
        twl = *(const float4*)(tw + l * 4);
        tbl = *(const float4*)(tb + l * 4);
    }

    float a1acc[8][4] = {};
    float nv[8] = {};
    float sacc = 0.f;

    for (int e = eb; e < ee; ++e) {
        const int s = srcS[e];
        float a[4];
        if (l < 16) {
            const float rt = relT[e];
            a[0] = __cosf(rt * twl.x + tbl.x);
            a[1] = __cosf(rt * twl.y + tbl.y);
            a[2] = __cosf(rt * twl.z + tbl.z);
            a[3] = __cosf(rt * twl.w + tbl.w);
        } else {
            const float4 m4 = *(const float4*)(msg + (size_t)orig[e] * 64 + (l - 16) * 4);
            a[0]=m4.x; a[1]=m4.y; a[2]=m4.z; a[3]=m4.w;
        }
        float part[8];
        #pragma unroll
        for (int h = 0; h < 8; ++h)
            part[h] = a[0]*gv[h][0] + a[1]*gv[h][1] + a[2]*gv[h][2] + a[3]*gv[h][3];
        {
            const unsigned short* kp = K1b + (size_t)s * 256 + l * 8;
            const float4 k0 = ld_bf16x4(kp), k1 = ld_bf16x4(kp + 4);
            part[hl] += q8[0]*k0.x + q8[1]*k0.y + q8[2]*k0.z + q8[3]*k0.w
                      + q8[4]*k1.x + q8[5]*k1.y + q8[6]*k1.z + q8[7]*k1.w;
        }
        #pragma unroll
        for (int mk = 1; mk < 32; mk <<= 1) {
            #pragma unroll
            for (int h = 0; h < 8; ++h)
                part[h] += __shfl_xor(part[h], mk);
        }
        const float pe = __expf(fminf(part[lane64 & 7] * RSQRT32, 80.f));
        float p_all[8];
        #pragma unroll
        for (int h = 0; h < 8; ++h)
            p_all[h] = __shfl(pe, (lane64 & 32) + h);
        #pragma unroll
        for (int h = 0; h < 8; ++h) {
            a1acc[h][0] += p_all[h]*a[0]; a1acc[h][1] += p_all[h]*a[1];
            a1acc[h][2] += p_all[h]*a[2]; a1acc[h][3] += p_all[h]*a[3];
        }
        {
            const unsigned short* vp = V1b + (size_t)s * 256 + l * 8;
            const float4 v0 = ld_bf16x4(vp), v1 = ld_bf16x4(vp + 4);
            const float pv = p_all[hl];
            nv[0] += pv*v0.x; nv[1] += pv*v0.y; nv[2] += pv*v0.z; nv[3] += pv*v0.w;
            nv[4] += pv*v1.x; nv[5] += pv*v1.y; nv[6] += pv*v1.z; nv[7] += pv*v1.w;
            sacc += pv;
        }
    }
    #pragma unroll
    for (int h = 0; h < 8; ++h)
        *(ushort4*)(A1b + (size_t)d * 1024 + h * 128 + l * 4) =
            st_bf16x4(a1acc[h][0], a1acc[h][1], a1acc[h][2], a1acc[h][3]);
    float* np = numv1 + (size_t)d * 256 + l * 8;
    *(float4*)(np)     = make_float4(nv[0], nv[1], nv[2], nv[3]);
    *(float4*)(np + 4) = make_float4(nv[4], nv[5], nv[6], nv[7]);
    if ((l & 3) == 0) s1[(size_t)d * 8 + hl] = sacc;
}

// ---------------- MFMA fold layer 1 ----------------
__global__ __launch_bounds__(256) void k_foldC1m(
    const unsigned short* __restrict__ A1b, const unsigned short* __restrict__ WF1,
    const float* __restrict__ numv1, const float* __restrict__ s1,
    const unsigned short* __restrict__ S1mb, unsigned short* __restrict__ hb)
{
    __shared__ unsigned short As[64 * 136];
    __shared__ unsigned short Bs[32 * 136];
    const int t = threadIdx.x;
    const int n0 = blockIdx.x * 64;
    const int h = blockIdx.y;
    {
        const int n = t >> 2, kk = (t & 3) * 32;
        const int gn = n0 + n;
        unsigned short* dst = As + n * 136 + kk;
        if (gn < NN) {
            const unsigned short* src = A1b + (size_t)gn * 1024 + h * 128 + kk;
            #pragma unroll
            for (int i = 0; i < 4; ++i)
                *(bf16x8*)(dst + 8 * i) = *(const bf16x8*)(src + 8 * i);
        } else {
            const bf16x8 z = {};
            #pragma unroll
            for (int i = 0; i < 4; ++i) *(bf16x8*)(dst + 8 * i) = z;
        }
    }
    {
        const int c = t >> 3, kk = (t & 7) * 16;
        const unsigned short* src = WF1 + (size_t)h * 4096 + c * 128 + kk;
        *(bf16x8*)(Bs + c * 136 + kk) = *(const bf16x8*)(src);
        *(bf16x8*)(Bs + c * 136 + kk + 8) = *(const bf16x8*)(src + 8);
    }
    __syncthreads();

    const int w = t >> 6, lane = t & 63, m = lane & 15, quad = lane >> 4;
    f32x4 acc[2];
    acc[0] = (f32x4){0.f, 0.f, 0.f, 0.f};
    acc[1] = (f32x4){0.f, 0.f, 0.f, 0.f};
    #pragma unroll
    for (int kc = 0; kc < 4; ++kc) {
        const bf16x8 af = *(const bf16x8*)(As + (16 * w + m) * 136 + kc * 32 + quad * 8);
        #pragma unroll
        for (int ct = 0; ct < 2; ++ct) {
            const bf16x8 bf = *(const bf16x8*)(Bs + (16 * ct + m) * 136 + kc * 32 + quad * 8);
            acc[ct] = MFMA_B16(af, bf, acc[ct]);
        }
    }
    #pragma unroll
    for (int ct = 0; ct < 2; ++ct) {
        const int c = ct * 16 + m;
        #pragma unroll
        for (int r = 0; r < 4; ++r) {
            const int gn = n0 + 16 * w + quad * 4 + r;
            if (gn < NN) {
                const float s = s1[(size_t)gn * 8 + h] + 1e-16f;
                const float nvv = numv1[(size_t)gn * 256 + h * 32 + c];
                const float sk = bf2f(S1mb[(size_t)gn * 256 + h * 32 + c]);
                float v = (acc[ct][r] + nvv) / s + sk;
                v = v > 0.f ? v : 0.f;
                hb[(size_t)gn * 256 + h * 32 + c] = f2bf(v);
            }
        }
    }
}

// ---------------- MFMA node GEMM layer 2 ----------------
__global__ __launch_bounds__(256) void k_gemm2m(
    const unsigned short* __restrict__ hb, const unsigned short* __restrict__ WB2,
    const float* __restrict__ c0, const float* __restrict__ c1,
    const float* __restrict__ c2, const float* __restrict__ c3,
    float* __restrict__ O0, float* __restrict__ O1,
    float* __restrict__ O2, float* __restrict__ O3)
{
    __shared__ unsigned short As[64 * 136];
    __shared__ unsigned short Bs[64 * 136];
    const int t = threadIdx.x;
    const int row0 = blockIdx.x * 64;
    const int coly = blockIdx.y;
    const int w = t >> 6, lane = t & 63, m = lane & 15, quad = lane >> 4;

    f32x4 acc[4];
    #pragma unroll
    for (int i = 0; i < 4; ++i) acc[i] = (f32x4){0.f, 0.f, 0.f, 0.f};

    for (int kb = 0; kb < 2; ++kb) {
        if (kb) __syncthreads();
        {
            const int r = t >> 2, kk = (t & 3) * 32;
            const int gr = row0 + r;
            unsigned short* dst = As + r * 136 + kk;
            if (gr < NN) {
                const unsigned short* src = hb + (size_t)gr * 256 + kb * 128 + kk;
                #pragma unroll
                for (int i = 0; i < 4; ++i)
                    *(bf16x8*)(dst + 8 * i) = *(const bf16x8*)(src + 8 * i);
            } else {
                const bf16x8 z = {};
                #pragma unroll
                for (int i = 0; i < 4; ++i) *(bf16x8*)(dst + 8 * i) = z;
            }
        }
        {
            const int n = t >> 2, kk = (t & 3) * 32;
            const unsigned short* src = WB2 + (size_t)(coly * 64 + n) * 256 + kb * 128 + kk;
            unsigned short* dst = Bs + n * 136 + kk;
            #pragma unroll
            for (int i = 0; i < 4; ++i)
                *(bf16x8*)(dst + 8 * i) = *(const bf16x8*)(src + 8 * i);
        }
        __syncthreads();
        #pragma unroll
        for (int kc = 0; kc < 4; ++kc) {
            const bf16x8 af = *(const bf16x8*)(As + (16 * w + m) * 136 + kc * 32 + quad * 8);
            #pragma unroll
            for (int ct = 0; ct < 4; ++ct) {
                const bf16x8 bf = *(const bf16x8*)(Bs + (16 * ct + m) * 136 + kc * 32 + quad * 8);
                acc[ct] = MFMA_B16(af, bf, acc[ct]);
            }
        }
    }
    #pragma unroll
    for (int ct = 0; ct < 4; ++ct) {
        const int col = coly * 64 + ct * 16 + m;
        const int part = col >> 5, pc = col & 31;
        const float* bb = part == 0 ? c0 : part == 1 ? c1 : part == 2 ? c2 : c3;
        float* Op = part == 0 ? O0 : part == 1 ? O1 : part == 2 ? O2 : O3;
        const float b = bb[pc];
        #pragma unroll
        for (int r = 0; r < 4; ++r) {
            const int gr = row0 + 16 * w + quad * 4 + r;
            if (gr < NN) Op[(size_t)gr * 32 + pc] = acc[ct][r] + b;
        }
    }
}

// ---------------- layer 2 fused p + aggregate ----------------
__global__ __launch_bounds__(256) void k_aggB2(
    const int* __restrict__ startA, const int* __restrict__ srcS,
    const int* __restrict__ orig, const float* __restrict__ relT,
    const float* __restrict__ msg, const float* __restrict__ tw,
    const float* __restrict__ tb,
    const float* __restrict__ Q2, const float* __restrict__ K2,
    const float* __restrict__ V2, const float* __restrict__ G2,
    float* __restrict__ A2, float* __restrict__ numv2, float* __restrict__ s2)
{
    const int t = threadIdx.x;
    const int g = t >> 5, l = t & 31;
    const int d = blockIdx.x * 8 + g;
    const int eb = startA[d], ee = startA[d + 1];

    const float q2l = Q2[(size_t)d * 32 + l];
    const float4 g2l = *(const float4*)(G2 + (size_t)d * 128 + l * 4);
    float4 twl = make_float4(0.f,0.f,0.f,0.f), tbl = twl;
    if (l < 16) {
        twl = *(const float4*)(tw + l * 4);
        tbl = *(const float4*)(tb + l * 4);
    }
    float acc2[4] = {};
    float nvacc = 0.f, sacc = 0.f;

    for (int e = eb; e < ee; ++e) {
        const int s = srcS[e];
        float a[4];
        if (l < 16) {
            const float rt = relT[e];
            a[0] = __cosf(rt * twl.x + tbl.x);
            a[1] = __cosf(rt * twl.y + tbl.y);
            a[2] = __cosf(rt * twl.z + tbl.z);
            a[3] = __cosf(rt * twl.w + tbl.w);
        } else {
            const float4 m4 = *(const float4*)(msg + (size_t)orig[e] * 64 + (l - 16) * 4);
            a[0] = m4.x; a[1] = m4.y; a[2] = m4.z; a[3] = m4.w;
        }
        float part = q2l * K2[(size_t)s * 32 + l];
        part += a[0] * g2l.x + a[1] * g2l.y + a[2] * g2l.z + a[3] * g2l.w;
        part += __shfl_xor(part, 1);
        part += __shfl_xor(part, 2);
        part += __shfl_xor(part, 4);
        part += __shfl_xor(part, 8);
        part += __shfl_xor(part, 16);
        const float p = __expf(fminf(part * RSQRT32, 80.f));
        acc2[0] += p * a[0]; acc2[1] += p * a[1];
        acc2[2] += p * a[2]; acc2[3] += p * a[3];
        nvacc += p * V2[(size_t)s * 32 + l];
        sacc += p;
    }
    *(float4*)(A2 + (size_t)d * 128 + l * 4) =
        make_float4(acc2[0], acc2[1], acc2[2], acc2[3]);
    numv2[(size_t)d * 32 + l] = nvacc;
    if (l == 0) s2[d] = sacc;
}

// ---------------- fold layer 2 ----------------
__global__ __launch_bounds__(256) void k_foldC2(
    const float* __restrict__ A2, const float* __restrict__ We2,
    const float* __restrict__ numv2, const float* __restrict__ s2,
    const float* __restrict__ S2m, float* __restrict__ out)
{
    __shared__ float Ws[128][36];
    const int t = threadIdx.x;
    {
        const int k = t >> 1, c16 = (t & 1) * 16;
        #pragma unroll
        for (int i = 0; i < 4; ++i)
            *(float4*)(&Ws[k][c16 + 4 * i]) =
                *(const float4*)(We2 + (size_t)k * 32 + c16 + 4 * i);
    }
    __syncthreads();
    const int n = blockIdx.x * 8 + (t >> 5);
    const int c = t & 31;
    const float* ap = A2 + (size_t)n * 128;
    float acc = 0.f;
    #pragma unroll 8
    for (int k = 0; k < 128; k += 4) {
        const float4 a4 = *(const float4*)(ap + k);
        acc += a4.x * Ws[k][c] + a4.y * Ws[k + 1][c] +
               a4.z * Ws[k + 2][c] + a4.w * Ws[k + 3][c];
    }
    const float s = s2[n] + 1e-16f;
    float v = (numv2[(size_t)n * 32 + c] + acc) / s + S2m[(size_t)n * 32 + c];
    out[(size_t)n * 32 + c] = v > 0.f ? v : 0.f;
}

extern "C" void kernel_launch(void* const* d_in, const int* in_sizes, int n_in,
                              void* d_out, int out_size, void* d_ws, size_t ws_size,
                              hipStream_t stream) {
    const float* x   = (const float*)d_in[0];
    const float* lu  = (const float*)d_in[1];
    const void*  ei  = d_in[2];
    const float* tE  = (const float*)d_in[3];
    const float* msg = (const float*)d_in[4];
    const float* tw  = (const float*)d_in[5];
    const float* tb  = (const float*)d_in[6];
    const float* Wq1 = (const float*)d_in[7];  const float* bq1 = (const float*)d_in[8];
    const float* Wk1 = (const float*)d_in[9];  const float* bk1 = (const float*)d_in[10];
    const float* Wv1 = (const float*)d_in[11]; const float* bv1 = (const float*)d_in[12];
    const float* We1 = (const float*)d_in[13];
    const float* Ws1 = (const float*)d_in[14]; const float* bs1 = (const float*)d_in[15];
    const float* Wq2 = (const float*)d_in[16]; const float* bq2 = (const float*)d_in[17];
    const float* Wk2 = (const float*)d_in[18]; const float* bk2 = (const float*)d_in[19];
    const float* Wv2 = (const float*)d_in[20]; const float* bv2 = (const float*)d_in[21];
    const float* We2 = (const float*)d_in[22];
    const float* Ws2 = (const float*)d_in[23]; const float* bs2 = (const float*)d_in[24];
    float* out = (float*)d_out;
    char* ws = (char*)d_ws;

    if (ws_size < WS_TOTAL) return;

    int* flag   = (int*)(ws + O_FLAG);
    int* bsum   = (int*)(ws + O_BSUM);
    int* srcI   = (int*)(ws + O_SRCI);
    int* dstI   = (int*)(ws + O_DSTI);
    int* deg    = (int*)(ws + O_DEG);
    int* cursor = (int*)(ws + O_CUR);
    int* startA = (int*)(ws + O_START);
    int* srcS   = (int*)(ws + O_SRCS);
    int* orig   = (int*)(ws + O_ORIG);
    float* relT = (float*)(ws + O_RELT);
    unsigned short* Q1b  = (unsigned short*)(ws + O_Q1);
    unsigned short* K1b  = (unsigned short*)(ws + O_K1);
    unsigned short* V1b  = (unsigned short*)(ws + O_V1);
    unsigned short* S1mb = (unsigned short*)(ws + O_S1M);
    unsigned short* G1b  = (unsigned short*)(ws + O_G1);
    unsigned short* A1b  = (unsigned short*)(ws + O_A1);   // exact overlay of G1b
    float* numv1 = (float*)(ws + O_NUMV1);
    float* s1    = (float*)(ws + O_S1);
    unsigned short* hb = (unsigned short*)(ws + O_H);
    float* Q2   = (float*)(ws + O_Q2);
    float* K2m  = (float*)(ws + O_K2);
    float* V2m  = (float*)(ws + O_V2);
    float* S2m  = (float*)(ws + O_S2M);
    float* G2   = (float*)(ws + O_G2);
    float* A2   = (float*)(ws + O_A2);
    float* numv2 = (float*)(ws + O_NUMV2);
    float* s2   = (float*)(ws + O_S2);
    unsigned short* WB1 = (unsigned short*)(ws + O_WB1);
    unsigned short* WG1 = (unsigned short*)(ws + O_WG1);
    unsigned short* WF1 = (unsigned short*)(ws + O_WF1);
    unsigned short* WB2 = (unsigned short*)(ws + O_WB2);

    hipMemsetAsync(ws + O_DEG, 0, 200000, stream);

    k_detect<<<1, 64, 0, stream>>>((const unsigned int*)ei, flag);
    k_convhist<<<(NE + 255) / 256, 256, 0, stream>>>(ei, flag, srcI, dstI, deg);
    k_scanA<<<196, 256, 0, stream>>>(deg, startA, bsum);
    k_scanB<<<1, 256, 0, stream>>>(bsum);
    k_scanC<<<196, 256, 0, stream>>>(deg, bsum, startA, cursor);
    k_scatter<<<(NE + 255) / 256, 256, 0, stream>>>(srcI, dstI, lu, tE, cursor,
                                                    srcS, orig, relT);
    k_prepw<<<896, 256, 0, stream>>>(Wq1, Wk1, Wv1, Ws1, We1, Wq2, Wk2, Wv2, Ws2,
                                     WB1, WG1, WF1, WB2);
    k_gemm1m<<<dim3(782, 16), 256, 0, stream>>>(
        x, WB1, bq1, bk1, bv1, bs1, Q1b, K1b, V1b, S1mb);
    k_g1m<<<dim3(782, 8), 256, 0, stream>>>(Q1b, WG1, G1b);
    k_agg1<<<NN / 8, 256, 0, stream>>>(startA, srcS, orig, relT, msg, tw, tb,
                                       Q1b, K1b, V1b, G1b, A1b, numv1, s1);
    k_foldC1m<<<dim3(782, 8), 256, 0, stream>>>(A1b, WF1, numv1, s1, S1mb, hb);
    k_gemm2m<<<dim3(782, 2), 256, 0, stream>>>(
        hb, WB2, bq2, bk2, bv2, bs2, Q2, K2m, V2m, S2m);
    k_g2<<<782, 256, 0, stream>>>(Q2, We2, G2);
    k_aggB2<<<NN / 8, 256, 0, stream>>>(startA, srcS, orig, relT, msg, tw, tb,
                                        Q2, K2m, V2m, G2, A2, numv2, s2);
    k_foldC2<<<NN / 8, 256, 0, stream>>>(A2, We2, numv2, s2, S2m, out);
}